// Round 1
// baseline (341.979 us; speedup 1.0000x reference)
//
#include <hip/hip_runtime.h>
#include <math.h>

#define HEADS 3
#define C_OUT 384
#define HC 1152      // HEADS*C_OUT
#define GAT_IN 24
#define HID 32
#define TSTEPS 12
#define NEG_SLOPE 0.2f
#define CAP 512

// ---------------- K1: h[n, o] = dot(xf[n,:], lin_w[o,:]) -------------------
__global__ __launch_bounds__(384) void k_lin(const float* __restrict__ xf,
                                             const float* __restrict__ lin_w,
                                             float* __restrict__ hbuf, int N) {
  int n = blockIdx.y;
  int o = blockIdx.x * 384 + threadIdx.x;
  const float4* xr = (const float4*)(xf + (size_t)n * GAT_IN);
  const float4* wr = (const float4*)(lin_w + (size_t)o * GAT_IN);
  float acc = 0.f;
#pragma unroll
  for (int j = 0; j < 6; ++j) {
    float4 a = xr[j], w = wr[j];
    acc += a.x * w.x + a.y * w.y + a.z * w.z + a.w * w.w;
  }
  hbuf[(size_t)n * HC + o] = acc;
}

// ---------------- K2: per-node attention logits ---------------------------
__global__ __launch_bounds__(256) void k_att(const float* __restrict__ hbuf,
                                             const float* __restrict__ att_src,
                                             const float* __restrict__ att_dst,
                                             float* __restrict__ a_src,
                                             float* __restrict__ a_dst, int N) {
  int node = blockIdx.x * 4 + (threadIdx.x >> 6);
  int lane = threadIdx.x & 63;
  if (node >= N) return;
  const float* hr = hbuf + (size_t)node * HC;
#pragma unroll
  for (int hh = 0; hh < HEADS; ++hh) {
    float as = 0.f, ad = 0.f;
    for (int c = lane; c < C_OUT; c += 64) {
      float v = hr[hh * C_OUT + c];
      as += v * att_src[hh * C_OUT + c];
      ad += v * att_dst[hh * C_OUT + c];
    }
#pragma unroll
    for (int off = 32; off >= 1; off >>= 1) {
      as += __shfl_xor(as, off, 64);
      ad += __shfl_xor(ad, off, 64);
    }
    if (lane == 0) {
      a_src[node * 3 + hh] = as;
      a_dst[node * 3 + hh] = ad;
    }
  }
}

// ---------------- CSR build ------------------------------------------------
__global__ void k_count(const int* __restrict__ edst, int* __restrict__ deg,
                        int E, int ET) {
  int e = blockIdx.x * blockDim.x + threadIdx.x;
  if (e >= ET) return;
  int d = (e < E) ? edst[e] : (e - E);
  atomicAdd(&deg[d], 1);
}

__global__ __launch_bounds__(1024) void k_scan(const int* __restrict__ deg,
                                               int* __restrict__ rowptr, int n) {
  __shared__ int buf[1024];
  int tid = threadIdx.x;
  int carry = 0;
  for (int base = 0; base < n; base += 1024) {
    int v = (base + tid < n) ? deg[base + tid] : 0;
    buf[tid] = v;
    __syncthreads();
    for (int off = 1; off < 1024; off <<= 1) {
      int add = (tid >= off) ? buf[tid - off] : 0;
      __syncthreads();
      buf[tid] += add;
      __syncthreads();
    }
    if (base + tid < n) rowptr[base + tid] = carry + buf[tid] - v;
    int total = buf[1023];
    __syncthreads();
    carry += total;
  }
  if (tid == 0) rowptr[n] = carry;
}

__global__ void k_scatter(const int* __restrict__ edst,
                          const int* __restrict__ rowptr,
                          int* __restrict__ cursor, int* __restrict__ elist,
                          int E, int ET) {
  int e = blockIdx.x * blockDim.x + threadIdx.x;
  if (e >= ET) return;
  int d = (e < E) ? edst[e] : (e - E);
  int pos = atomicAdd(&cursor[d], 1);
  elist[rowptr[d] + pos] = e;
}

// ---------------- K6: edge softmax + aggregation per dst node --------------
__device__ __forceinline__ float lrelu(float x) {
  return x >= 0.f ? x : NEG_SLOPE * x;
}

__global__ __launch_bounds__(384) void k_agg(
    const float* __restrict__ hbuf, const float* __restrict__ a_src,
    const float* __restrict__ a_dst, const int* __restrict__ esrc,
    const int* __restrict__ elist, const int* __restrict__ rowptr,
    const float* __restrict__ gat_bias, float* __restrict__ gat_out, int E,
    int N) {
  __shared__ int s_src[CAP];
  __shared__ float s_w[CAP * 3];
  __shared__ float wred[6][3];
  __shared__ float s_sc[6];
  int n = blockIdx.x;
  int tid = threadIdx.x, lane = tid & 63, wv = tid >> 6;
  int start = rowptr[n], deg = rowptr[n + 1] - start;
  float ad0 = a_dst[n * 3 + 0], ad1 = a_dst[n * 3 + 1], ad2 = a_dst[n * 3 + 2];
  bool cached = (deg <= CAP);

  // pass 1: alphas + max
  float m0 = -1e30f, m1 = -1e30f, m2 = -1e30f;
  for (int i = tid; i < deg; i += 384) {
    int e = elist[start + i];
    int s = (e < E) ? esrc[e] : (e - E);
    float x0 = lrelu(a_src[s * 3 + 0] + ad0);
    float x1 = lrelu(a_src[s * 3 + 1] + ad1);
    float x2 = lrelu(a_src[s * 3 + 2] + ad2);
    if (cached) {
      s_src[i] = s;
      s_w[i * 3] = x0;
      s_w[i * 3 + 1] = x1;
      s_w[i * 3 + 2] = x2;
    }
    m0 = fmaxf(m0, x0);
    m1 = fmaxf(m1, x1);
    m2 = fmaxf(m2, x2);
  }
#pragma unroll
  for (int off = 32; off >= 1; off >>= 1) {
    m0 = fmaxf(m0, __shfl_xor(m0, off, 64));
    m1 = fmaxf(m1, __shfl_xor(m1, off, 64));
    m2 = fmaxf(m2, __shfl_xor(m2, off, 64));
  }
  if (lane == 0) { wred[wv][0] = m0; wred[wv][1] = m1; wred[wv][2] = m2; }
  __syncthreads();
  if (tid < 3) {
    float m = wred[0][tid];
#pragma unroll
    for (int q = 1; q < 6; ++q) m = fmaxf(m, wred[q][tid]);
    s_sc[tid] = m;
  }
  __syncthreads();
  m0 = s_sc[0]; m1 = s_sc[1]; m2 = s_sc[2];

  // pass 2: exp + denom
  float t0 = 0.f, t1 = 0.f, t2 = 0.f;
  for (int i = tid; i < deg; i += 384) {
    float x0, x1, x2;
    if (cached) {
      x0 = s_w[i * 3]; x1 = s_w[i * 3 + 1]; x2 = s_w[i * 3 + 2];
    } else {
      int e = elist[start + i];
      int s = (e < E) ? esrc[e] : (e - E);
      x0 = lrelu(a_src[s * 3 + 0] + ad0);
      x1 = lrelu(a_src[s * 3 + 1] + ad1);
      x2 = lrelu(a_src[s * 3 + 2] + ad2);
    }
    float e0 = expf(x0 - m0), e1 = expf(x1 - m1), e2 = expf(x2 - m2);
    if (cached) { s_w[i * 3] = e0; s_w[i * 3 + 1] = e1; s_w[i * 3 + 2] = e2; }
    t0 += e0; t1 += e1; t2 += e2;
  }
#pragma unroll
  for (int off = 32; off >= 1; off >>= 1) {
    t0 += __shfl_xor(t0, off, 64);
    t1 += __shfl_xor(t1, off, 64);
    t2 += __shfl_xor(t2, off, 64);
  }
  if (lane == 0) { wred[wv][0] = t0; wred[wv][1] = t1; wred[wv][2] = t2; }
  __syncthreads();
  if (tid < 3) {
    float ssum = 0.f;
#pragma unroll
    for (int q = 0; q < 6; ++q) ssum += wred[q][tid];
    s_sc[3 + tid] = 1.0f / ssum;
  }
  __syncthreads();
  float inv0 = s_sc[3], inv1 = s_sc[4], inv2 = s_sc[5];

  // pass 3: weighted aggregation, head-mean fused
  float acc0 = 0.f, acc1 = 0.f, acc2 = 0.f;
  if (cached) {
    for (int i = 0; i < deg; ++i) {
      int s = s_src[i];
      const float* hr = hbuf + (size_t)s * HC;
      float w0 = s_w[i * 3] * inv0;
      float w1 = s_w[i * 3 + 1] * inv1;
      float w2 = s_w[i * 3 + 2] * inv2;
      acc0 += w0 * hr[tid];
      acc1 += w1 * hr[C_OUT + tid];
      acc2 += w2 * hr[2 * C_OUT + tid];
    }
  } else {
    for (int i = 0; i < deg; ++i) {
      int e = elist[start + i];
      int s = (e < E) ? esrc[e] : (e - E);
      float x0 = lrelu(a_src[s * 3 + 0] + ad0);
      float x1 = lrelu(a_src[s * 3 + 1] + ad1);
      float x2 = lrelu(a_src[s * 3 + 2] + ad2);
      float w0 = expf(x0 - m0) * inv0;
      float w1 = expf(x1 - m1) * inv1;
      float w2 = expf(x2 - m2) * inv2;
      const float* hr = hbuf + (size_t)s * HC;
      acc0 += w0 * hr[tid];
      acc1 += w1 * hr[C_OUT + tid];
      acc2 += w2 * hr[2 * C_OUT + tid];
    }
  }
  gat_out[(size_t)n * C_OUT + tid] =
      (acc0 + acc1 + acc2) * (1.f / 3.f) + gat_bias[tid];
}

// ---------------- K7: GRU + projections, 4 nodes per 512-thread block ------
__global__ __launch_bounds__(512) void k_gru(
    const float* __restrict__ gat, const float* __restrict__ w_ih,
    const float* __restrict__ w_hh, const float* __restrict__ b_ih,
    const float* __restrict__ b_hh, const float* __restrict__ p1w,
    const float* __restrict__ p1b, const float* __restrict__ p2w,
    const float* __restrict__ p2b, float* __restrict__ out, int N) {
  __shared__ float s_wih[96][33];  // +1 pad: kills 32-way bank conflict
  __shared__ float s_whh[96][33];
  __shared__ float s_bih[96], s_bhh[96], s_p1w[32], s_p2w[144], s_p2b[12];
  __shared__ float s_xt[4][32], s_h[4][32], s_gi[4][96], s_gh[4][96], s_o[4][12];
  int tid = threadIdx.x;
  for (int i = tid; i < 96 * 32; i += 512) {
    s_wih[i >> 5][i & 31] = w_ih[i];
    s_whh[i >> 5][i & 31] = w_hh[i];
  }
  if (tid < 96) { s_bih[tid] = b_ih[tid]; s_bhh[tid] = b_hh[tid]; }
  if (tid < 32) s_p1w[tid] = p1w[tid];
  if (tid < 144) s_p2w[tid] = p2w[tid];
  if (tid < 12) s_p2b[tid] = p2b[tid];
  int g = tid >> 7, tg = tid & 127;
  int node = blockIdx.x * 4 + g;
  bool valid = node < N;
  if (valid && tg < 32) s_h[g][tg] = 0.f;
  float p1b0 = p1b[0];
  __syncthreads();
  for (int t = 0; t < TSTEPS; ++t) {
    if (valid && tg >= 96) s_xt[g][tg - 96] = gat[(size_t)node * C_OUT + t * HID + (tg - 96)];
    __syncthreads();
    if (valid && tg < 96) {
      float gi = s_bih[tg], gh = s_bhh[tg];
#pragma unroll
      for (int k = 0; k < HID; ++k) {
        gi += s_xt[g][k] * s_wih[tg][k];
        gh += s_h[g][k] * s_whh[tg][k];
      }
      s_gi[g][tg] = gi;
      s_gh[g][tg] = gh;
    }
    __syncthreads();
    if (valid && tg < 32) {
      int k = tg;
      float r = 1.f / (1.f + expf(-(s_gi[g][k] + s_gh[g][k])));
      float z = 1.f / (1.f + expf(-(s_gi[g][32 + k] + s_gh[g][32 + k])));
      float nn = tanhf(s_gi[g][64 + k] + r * s_gh[g][64 + k]);
      float hnew = (1.f - z) * nn + z * s_h[g][k];
      s_h[g][k] = hnew;
      float part = hnew * s_p1w[k];
#pragma unroll
      for (int off = 16; off >= 1; off >>= 1) part += __shfl_xor(part, off, 64);
      if (k == 0) s_o[g][t] = part + p1b0;
    }
    __syncthreads();
  }
  if (valid && tg < 12) {
    float acc = s_p2b[tg];
#pragma unroll
    for (int s2 = 0; s2 < TSTEPS; ++s2) acc += s_p2w[tg * 12 + s2] * s_o[g][s2];
    out[(size_t)node * 12 + tg] = acc;
  }
}

// ---------------------------------------------------------------------------
extern "C" void kernel_launch(void* const* d_in, const int* in_sizes, int n_in,
                              void* d_out, int out_size, void* d_ws,
                              size_t ws_size, hipStream_t stream) {
  const float* x = (const float*)d_in[0];
  const int* ei = (const int*)d_in[1];
  const float* lin_w = (const float*)d_in[2];
  const float* att_src = (const float*)d_in[3];
  const float* att_dst = (const float*)d_in[4];
  const float* gat_bias = (const float*)d_in[5];
  const float* w_ih = (const float*)d_in[6];
  const float* w_hh = (const float*)d_in[7];
  const float* b_ih = (const float*)d_in[8];
  const float* b_hh = (const float*)d_in[9];
  const float* p1w = (const float*)d_in[10];
  const float* p1b = (const float*)d_in[11];
  const float* p2w = (const float*)d_in[12];
  const float* p2b = (const float*)d_in[13];

  int N = in_sizes[0] / GAT_IN;  // 10000
  int E = in_sizes[1] / 2;       // 160000
  int ET = E + N;

  size_t off = 0;
  char* base = (char*)d_ws;
  auto alloc = [&](size_t bytes) {
    void* p = base + off;
    off += (bytes + 255) & ~(size_t)255;
    return p;
  };
  float* hbuf = (float*)alloc((size_t)N * HC * 4);
  float* gatb = (float*)alloc((size_t)N * C_OUT * 4);
  float* a_srcb = (float*)alloc((size_t)N * 3 * 4);
  float* a_dstb = (float*)alloc((size_t)N * 3 * 4);
  int* deg = (int*)alloc((size_t)N * 4);
  int* rowptr = (int*)alloc((size_t)(N + 1) * 4);
  int* cursor = (int*)alloc((size_t)N * 4);
  int* elist = (int*)alloc((size_t)ET * 4);
  (void)ws_size;
  (void)n_in;
  (void)out_size;

  hipMemsetAsync(deg, 0, (size_t)N * 4, stream);
  hipMemsetAsync(cursor, 0, (size_t)N * 4, stream);

  dim3 g1(3, N);
  k_lin<<<g1, 384, 0, stream>>>(x, lin_w, hbuf, N);
  k_att<<<(N + 3) / 4, 256, 0, stream>>>(hbuf, att_src, att_dst, a_srcb,
                                         a_dstb, N);
  k_count<<<(ET + 255) / 256, 256, 0, stream>>>(ei + E, deg, E, ET);
  k_scan<<<1, 1024, 0, stream>>>(deg, rowptr, N);
  k_scatter<<<(ET + 255) / 256, 256, 0, stream>>>(ei + E, rowptr, cursor,
                                                  elist, E, ET);
  k_agg<<<N, 384, 0, stream>>>(hbuf, a_srcb, a_dstb, ei, elist, rowptr,
                               gat_bias, gatb, E, N);
  k_gru<<<(N + 3) / 4, 512, 0, stream>>>(gatb, w_ih, w_hh, b_ih, b_hh, p1w,
                                         p1b, p2w, p2b, (float*)d_out, N);
}

// Round 2
// 248.543 us; speedup vs baseline: 1.3759x; 1.3759x over previous
//
#include <hip/hip_runtime.h>
#include <math.h>

#define HEADS 3
#define C_OUT 384
#define HC 1152      // HEADS*C_OUT
#define GAT_IN 24
#define HID 32
#define TSTEPS 12
#define NEG_SLOPE 0.2f
#define CAP 512

__device__ __forceinline__ float sigm(float x) {
  return 1.f / (1.f + __expf(-x));
}
__device__ __forceinline__ float tanh_fast(float x) {
  // 2*sigmoid(2x)-1 ; safe for all finite x (exp->inf gives -1)
  return 2.f / (1.f + __expf(-2.f * x)) - 1.f;
}

// ---------------- K1: h = xf @ lin_w.T, weights in registers ---------------
__global__ __launch_bounds__(384) void k_lin(const float* __restrict__ xf,
                                             const float* __restrict__ lin_w,
                                             float* __restrict__ hbuf, int N,
                                             int chunk) {
  int o = blockIdx.x * 384 + threadIdx.x;  // 0..1151
  int n0 = blockIdx.y * chunk;
  int n1 = min(n0 + chunk, N);
  float4 w[6];
  const float4* wr = (const float4*)(lin_w + (size_t)o * GAT_IN);
#pragma unroll
  for (int j = 0; j < 6; ++j) w[j] = wr[j];
  for (int n = n0; n < n1; ++n) {
    const float4* xr = (const float4*)(xf + (size_t)n * GAT_IN);
    float acc = 0.f;
#pragma unroll
    for (int j = 0; j < 6; ++j) {
      float4 a = xr[j];
      acc += a.x * w[j].x + a.y * w[j].y + a.z * w[j].z + a.w * w[j].w;
    }
    hbuf[(size_t)n * HC + o] = acc;
  }
}

// ---------------- K2: per-node attention logits ---------------------------
__global__ __launch_bounds__(256) void k_att(const float* __restrict__ hbuf,
                                             const float* __restrict__ att_src,
                                             const float* __restrict__ att_dst,
                                             float* __restrict__ a_src,
                                             float* __restrict__ a_dst, int N) {
  int node = blockIdx.x * 4 + (threadIdx.x >> 6);
  int lane = threadIdx.x & 63;
  if (node >= N) return;
  const float* hr = hbuf + (size_t)node * HC;
#pragma unroll
  for (int hh = 0; hh < HEADS; ++hh) {
    float as = 0.f, ad = 0.f;
    for (int c = lane; c < C_OUT; c += 64) {
      float v = hr[hh * C_OUT + c];
      as += v * att_src[hh * C_OUT + c];
      ad += v * att_dst[hh * C_OUT + c];
    }
#pragma unroll
    for (int off = 32; off >= 1; off >>= 1) {
      as += __shfl_xor(as, off, 64);
      ad += __shfl_xor(ad, off, 64);
    }
    if (lane == 0) {
      a_src[node * 3 + hh] = as;
      a_dst[node * 3 + hh] = ad;
    }
  }
}

// ---------------- CSR build ------------------------------------------------
__global__ void k_count(const int* __restrict__ edst, int* __restrict__ deg,
                        int E, int ET) {
  int e = blockIdx.x * blockDim.x + threadIdx.x;
  if (e >= ET) return;
  int d = (e < E) ? edst[e] : (e - E);
  atomicAdd(&deg[d], 1);
}

__global__ __launch_bounds__(1024) void k_scan(const int* __restrict__ deg,
                                               int* __restrict__ rowptr,
                                               int n) {
  __shared__ int s_wt[16];
  int tid = threadIdx.x, lane = tid & 63, w = tid >> 6;
  int carry = 0;
  for (int base = 0; base < n; base += 1024) {
    int idx = base + tid;
    int orig = (idx < n) ? deg[idx] : 0;
    int v = orig;
#pragma unroll
    for (int off = 1; off < 64; off <<= 1) {
      int t = __shfl_up(v, off, 64);
      if (lane >= off) v += t;
    }
    if (lane == 63) s_wt[w] = v;
    __syncthreads();
    if (w == 0) {
      int x = (lane < 16) ? s_wt[lane] : 0;
#pragma unroll
      for (int off = 1; off < 16; off <<= 1) {
        int t = __shfl_up(x, off, 64);
        if (lane >= off) x += t;
      }
      if (lane < 16) s_wt[lane] = x;
    }
    __syncthreads();
    int wexcl = (w == 0) ? 0 : s_wt[w - 1];
    int total = s_wt[15];
    if (idx < n) rowptr[idx] = carry + wexcl + v - orig;
    carry += total;
    __syncthreads();
  }
  if (tid == 0) rowptr[n] = carry;
}

__global__ void k_scatter(const int* __restrict__ edst,
                          const int* __restrict__ rowptr,
                          int* __restrict__ cursor, int* __restrict__ elist,
                          int E, int ET) {
  int e = blockIdx.x * blockDim.x + threadIdx.x;
  if (e >= ET) return;
  int d = (e < E) ? edst[e] : (e - E);
  int pos = atomicAdd(&cursor[d], 1);
  elist[rowptr[d] + pos] = e;
}

// ---------------- K6: edge softmax + aggregation per dst node --------------
__device__ __forceinline__ float lrelu(float x) {
  return x >= 0.f ? x : NEG_SLOPE * x;
}

__global__ __launch_bounds__(384) void k_agg(
    const float* __restrict__ hbuf, const float* __restrict__ a_src,
    const float* __restrict__ a_dst, const int* __restrict__ esrc,
    const int* __restrict__ elist, const int* __restrict__ rowptr,
    const float* __restrict__ gat_bias, float* __restrict__ gat_out, int E,
    int N) {
  __shared__ int s_src[CAP];
  __shared__ float s_w[CAP * 3];
  __shared__ float wred[6][3];
  __shared__ float s_sc[6];
  int n = blockIdx.x;
  int tid = threadIdx.x, lane = tid & 63, wv = tid >> 6;
  int start = rowptr[n], deg = rowptr[n + 1] - start;
  float ad0 = a_dst[n * 3 + 0], ad1 = a_dst[n * 3 + 1], ad2 = a_dst[n * 3 + 2];
  bool cached = (deg <= CAP);

  float m0 = -1e30f, m1 = -1e30f, m2 = -1e30f;
  for (int i = tid; i < deg; i += 384) {
    int e = elist[start + i];
    int s = (e < E) ? esrc[e] : (e - E);
    float x0 = lrelu(a_src[s * 3 + 0] + ad0);
    float x1 = lrelu(a_src[s * 3 + 1] + ad1);
    float x2 = lrelu(a_src[s * 3 + 2] + ad2);
    if (cached) {
      s_src[i] = s;
      s_w[i * 3] = x0;
      s_w[i * 3 + 1] = x1;
      s_w[i * 3 + 2] = x2;
    }
    m0 = fmaxf(m0, x0);
    m1 = fmaxf(m1, x1);
    m2 = fmaxf(m2, x2);
  }
#pragma unroll
  for (int off = 32; off >= 1; off >>= 1) {
    m0 = fmaxf(m0, __shfl_xor(m0, off, 64));
    m1 = fmaxf(m1, __shfl_xor(m1, off, 64));
    m2 = fmaxf(m2, __shfl_xor(m2, off, 64));
  }
  if (lane == 0) { wred[wv][0] = m0; wred[wv][1] = m1; wred[wv][2] = m2; }
  __syncthreads();
  if (tid < 3) {
    float m = wred[0][tid];
#pragma unroll
    for (int q = 1; q < 6; ++q) m = fmaxf(m, wred[q][tid]);
    s_sc[tid] = m;
  }
  __syncthreads();
  m0 = s_sc[0]; m1 = s_sc[1]; m2 = s_sc[2];

  float t0 = 0.f, t1 = 0.f, t2 = 0.f;
  for (int i = tid; i < deg; i += 384) {
    float x0, x1, x2;
    if (cached) {
      x0 = s_w[i * 3]; x1 = s_w[i * 3 + 1]; x2 = s_w[i * 3 + 2];
    } else {
      int e = elist[start + i];
      int s = (e < E) ? esrc[e] : (e - E);
      x0 = lrelu(a_src[s * 3 + 0] + ad0);
      x1 = lrelu(a_src[s * 3 + 1] + ad1);
      x2 = lrelu(a_src[s * 3 + 2] + ad2);
    }
    float e0 = expf(x0 - m0), e1 = expf(x1 - m1), e2 = expf(x2 - m2);
    if (cached) { s_w[i * 3] = e0; s_w[i * 3 + 1] = e1; s_w[i * 3 + 2] = e2; }
    t0 += e0; t1 += e1; t2 += e2;
  }
#pragma unroll
  for (int off = 32; off >= 1; off >>= 1) {
    t0 += __shfl_xor(t0, off, 64);
    t1 += __shfl_xor(t1, off, 64);
    t2 += __shfl_xor(t2, off, 64);
  }
  if (lane == 0) { wred[wv][0] = t0; wred[wv][1] = t1; wred[wv][2] = t2; }
  __syncthreads();
  if (tid < 3) {
    float ssum = 0.f;
#pragma unroll
    for (int q = 0; q < 6; ++q) ssum += wred[q][tid];
    s_sc[3 + tid] = 1.0f / ssum;
  }
  __syncthreads();
  float inv0 = s_sc[3], inv1 = s_sc[4], inv2 = s_sc[5];

  float acc0 = 0.f, acc1 = 0.f, acc2 = 0.f;
  if (cached) {
    for (int i = 0; i < deg; ++i) {
      int s = s_src[i];
      const float* hr = hbuf + (size_t)s * HC;
      float w0 = s_w[i * 3] * inv0;
      float w1 = s_w[i * 3 + 1] * inv1;
      float w2 = s_w[i * 3 + 2] * inv2;
      acc0 += w0 * hr[tid];
      acc1 += w1 * hr[C_OUT + tid];
      acc2 += w2 * hr[2 * C_OUT + tid];
    }
  } else {
    for (int i = 0; i < deg; ++i) {
      int e = elist[start + i];
      int s = (e < E) ? esrc[e] : (e - E);
      float x0 = lrelu(a_src[s * 3 + 0] + ad0);
      float x1 = lrelu(a_src[s * 3 + 1] + ad1);
      float x2 = lrelu(a_src[s * 3 + 2] + ad2);
      float w0 = expf(x0 - m0) * inv0;
      float w1 = expf(x1 - m1) * inv1;
      float w2 = expf(x2 - m2) * inv2;
      const float* hr = hbuf + (size_t)s * HC;
      acc0 += w0 * hr[tid];
      acc1 += w1 * hr[C_OUT + tid];
      acc2 += w2 * hr[2 * C_OUT + tid];
    }
  }
  gat_out[(size_t)n * C_OUT + tid] =
      (acc0 + acc1 + acc2) * (1.f / 3.f) + gat_bias[tid];
}

// ---------------- K7a: gi = gat(as [R][32]) @ w_ih.T + b_ih ---------------
// R = N*12 rows, 96 cols. Tile 64 rows x 96 cols per 128-thread block,
// micro-tile 8x6 per thread, transposed LDS operands.
__global__ __launch_bounds__(128) void k_gi(const float* __restrict__ A,
                                            const float* __restrict__ wih,
                                            const float* __restrict__ bih,
                                            float* __restrict__ gi, int R) {
  __shared__ float At[32][68];   // stride 68 floats = 272B (16B-mult)
  __shared__ float Bt[32][100];  // stride 100 floats = 400B (16B-mult)
  __shared__ float s_bias[96];
  int tid = threadIdx.x;
  int row0 = blockIdx.x * 64;
  {
    int r = tid >> 3;              // 0..15
    int kq = (tid & 7) * 4;        // 0..28
    for (int rr = 0; rr < 64; rr += 16) {
      int row = row0 + rr + r;
      int rc = min(row, R - 1);
      float4 a = *(const float4*)(A + (size_t)rc * 32 + kq);
      At[kq + 0][rr + r] = a.x;
      At[kq + 1][rr + r] = a.y;
      At[kq + 2][rr + r] = a.z;
      At[kq + 3][rr + r] = a.w;
    }
  }
#pragma unroll
  for (int q = 0; q < 6; ++q) {
    int fid = q * 128 + tid;  // 0..767
    int c = fid >> 3;
    int k4 = (fid & 7) * 4;
    float4 b = *(const float4*)(wih + (size_t)c * 32 + k4);
    Bt[k4 + 0][c] = b.x;
    Bt[k4 + 1][c] = b.y;
    Bt[k4 + 2][c] = b.z;
    Bt[k4 + 3][c] = b.w;
  }
  if (tid < 96) s_bias[tid] = bih[tid];
  __syncthreads();
  int rowg = tid & 7;   // 8 row-groups x 8 rows
  int colg = tid >> 3;  // 16 col-groups x 6 cols
  int r0 = rowg * 8, c0 = colg * 6;
  float acc[8][6];
#pragma unroll
  for (int i = 0; i < 8; ++i)
#pragma unroll
    for (int j = 0; j < 6; ++j) acc[i][j] = 0.f;
#pragma unroll 4
  for (int k = 0; k < 32; ++k) {
    float4 a0 = *(const float4*)&At[k][r0];
    float4 a1 = *(const float4*)&At[k][r0 + 4];
    float b[6];
#pragma unroll
    for (int j = 0; j < 6; ++j) b[j] = Bt[k][c0 + j];
    float av[8] = {a0.x, a0.y, a0.z, a0.w, a1.x, a1.y, a1.z, a1.w};
#pragma unroll
    for (int i = 0; i < 8; ++i)
#pragma unroll
      for (int j = 0; j < 6; ++j) acc[i][j] += av[i] * b[j];
  }
#pragma unroll
  for (int i = 0; i < 8; ++i) {
    int row = row0 + r0 + i;
    if (row < R) {
      float* crow = gi + (size_t)row * 96 + c0;
#pragma unroll
      for (int j = 0; j < 6; ++j) crow[j] = acc[i][j] + s_bias[c0 + j];
    }
  }
}

// ---------------- K7b: GRU recurrence + projections ------------------------
// One node per 32-lane half-wave; w_hh rows in 96 regs/lane; no barriers.
__global__ __launch_bounds__(256) void k_rec(
    const float* __restrict__ gi, const float* __restrict__ whh,
    const float* __restrict__ bhh, const float* __restrict__ p1w,
    const float* __restrict__ p1b, const float* __restrict__ p2w,
    const float* __restrict__ p2b, float* __restrict__ out, int N) {
  __shared__ float h_hist[8][13][36];  // stride 36 floats = 144B (16B-mult)
  __shared__ float s_o[8][12];
  int tid = threadIdx.x;
  int nd = tid >> 5;   // node slot 0..7
  int k = tid & 31;    // hidden unit
  int node = blockIdx.x * 8 + nd;
  if (node >= N) return;  // no barriers below -> safe

  float wr[32], wz[32], wn[32];
  {
    const float4* pr = (const float4*)(whh + (size_t)k * HID);
    const float4* pz = (const float4*)(whh + (size_t)(HID + k) * HID);
    const float4* pn = (const float4*)(whh + (size_t)(2 * HID + k) * HID);
#pragma unroll
    for (int j = 0; j < 8; ++j) {
      float4 a = pr[j], b = pz[j], c = pn[j];
      wr[4 * j] = a.x; wr[4 * j + 1] = a.y; wr[4 * j + 2] = a.z; wr[4 * j + 3] = a.w;
      wz[4 * j] = b.x; wz[4 * j + 1] = b.y; wz[4 * j + 2] = b.z; wz[4 * j + 3] = b.w;
      wn[4 * j] = c.x; wn[4 * j + 1] = c.y; wn[4 * j + 2] = c.z; wn[4 * j + 3] = c.w;
    }
  }
  float bhr = bhh[k], bhz = bhh[HID + k], bhn = bhh[2 * HID + k];
  h_hist[nd][0][k] = 0.f;
  float h = 0.f;
  const float* girow = gi + (size_t)node * TSTEPS * 96;
  for (int t = 0; t < TSTEPS; ++t) {
    float gr = girow[t * 96 + k];
    float gz = girow[t * 96 + 32 + k];
    float gn = girow[t * 96 + 64 + k];
    float ar = 0.f, az = 0.f, an = 0.f;
    const float* hh = &h_hist[nd][t][0];
#pragma unroll
    for (int q = 0; q < 8; ++q) {
      float4 hp = *(const float4*)(hh + q * 4);
      ar += wr[4 * q] * hp.x + wr[4 * q + 1] * hp.y + wr[4 * q + 2] * hp.z +
            wr[4 * q + 3] * hp.w;
      az += wz[4 * q] * hp.x + wz[4 * q + 1] * hp.y + wz[4 * q + 2] * hp.z +
            wz[4 * q + 3] * hp.w;
      an += wn[4 * q] * hp.x + wn[4 * q + 1] * hp.y + wn[4 * q + 2] * hp.z +
            wn[4 * q + 3] * hp.w;
    }
    float r = sigm(gr + ar + bhr);
    float z = sigm(gz + az + bhz);
    float nn = tanh_fast(gn + r * (an + bhn));
    float hnew = (1.f - z) * nn + z * h;
    h = hnew;
    h_hist[nd][t + 1][k] = hnew;
  }
  // projections (same-wave LDS ordering; lanes t<12 of each half-wave)
  if (k < TSTEPS) {
    float o = p1b[0];
#pragma unroll
    for (int kk = 0; kk < HID; ++kk) o += h_hist[nd][k + 1][kk] * p1w[kk];
    s_o[nd][k] = o;
  }
  if (k < TSTEPS) {
    float acc = p2b[k];
#pragma unroll
    for (int s2 = 0; s2 < TSTEPS; ++s2)
      acc += p2w[k * TSTEPS + s2] * s_o[nd][s2];
    out[(size_t)node * TSTEPS + k] = acc;
  }
}

// ---------------------------------------------------------------------------
extern "C" void kernel_launch(void* const* d_in, const int* in_sizes, int n_in,
                              void* d_out, int out_size, void* d_ws,
                              size_t ws_size, hipStream_t stream) {
  const float* x = (const float*)d_in[0];
  const int* ei = (const int*)d_in[1];
  const float* lin_w = (const float*)d_in[2];
  const float* att_src = (const float*)d_in[3];
  const float* att_dst = (const float*)d_in[4];
  const float* gat_bias = (const float*)d_in[5];
  const float* w_ih = (const float*)d_in[6];
  const float* w_hh = (const float*)d_in[7];
  const float* b_ih = (const float*)d_in[8];
  const float* b_hh = (const float*)d_in[9];
  const float* p1w = (const float*)d_in[10];
  const float* p1b = (const float*)d_in[11];
  const float* p2w = (const float*)d_in[12];
  const float* p2b = (const float*)d_in[13];

  int N = in_sizes[0] / GAT_IN;  // 10000
  int E = in_sizes[1] / 2;       // 160000
  int ET = E + N;
  int R = N * TSTEPS;            // 120000

  size_t off = 0;
  char* base = (char*)d_ws;
  auto alloc = [&](size_t bytes) {
    void* p = base + off;
    off += (bytes + 255) & ~(size_t)255;
    return p;
  };
  float* hbuf = (float*)alloc((size_t)N * HC * 4);  // also reused as gi
  float* gatb = (float*)alloc((size_t)N * C_OUT * 4);
  float* a_srcb = (float*)alloc((size_t)N * 3 * 4);
  float* a_dstb = (float*)alloc((size_t)N * 3 * 4);
  int* deg = (int*)alloc((size_t)N * 4);
  int* rowptr = (int*)alloc((size_t)(N + 1) * 4);
  int* cursor = (int*)alloc((size_t)N * 4);
  int* elist = (int*)alloc((size_t)ET * 4);
  float* gib = hbuf;  // alias: hbuf (N*1152) dead after k_agg; gi = N*12*96
  (void)ws_size; (void)n_in; (void)out_size;

  hipMemsetAsync(deg, 0, (size_t)N * 4, stream);
  hipMemsetAsync(cursor, 0, (size_t)N * 4, stream);

  int chunk = (N + 199) / 200;
  dim3 g1(3, 200);
  k_lin<<<g1, 384, 0, stream>>>(x, lin_w, hbuf, N, chunk);
  k_att<<<(N + 3) / 4, 256, 0, stream>>>(hbuf, att_src, att_dst, a_srcb,
                                         a_dstb, N);
  k_count<<<(ET + 255) / 256, 256, 0, stream>>>(ei + E, deg, E, ET);
  k_scan<<<1, 1024, 0, stream>>>(deg, rowptr, N);
  k_scatter<<<(ET + 255) / 256, 256, 0, stream>>>(ei + E, rowptr, cursor,
                                                  elist, E, ET);
  k_agg<<<N, 384, 0, stream>>>(hbuf, a_srcb, a_dstb, ei, elist, rowptr,
                               gat_bias, gatb, E, N);
  k_gi<<<(R + 63) / 64, 128, 0, stream>>>(gatb, w_ih, b_ih, gib, R);
  k_rec<<<(N + 7) / 8, 256, 0, stream>>>(gib, w_hh, b_hh, p1w, p1b, p2w, p2b,
                                         (float*)d_out, N);
}

// Round 3
// 190.031 us; speedup vs baseline: 1.7996x; 1.3079x over previous
//
#include <hip/hip_runtime.h>
#include <math.h>

#define HEADS 3
#define C_OUT 384
#define HC 1152      // HEADS*C_OUT
#define GAT_IN 24
#define HID 32
#define TSTEPS 12
#define NEG_SLOPE 0.2f
#define CAP 512
#define LIN_CHUNK 25

__device__ __forceinline__ float sigm(float x) {
  return 1.f / (1.f + __expf(-x));
}
__device__ __forceinline__ float tanh_fast(float x) {
  return 2.f / (1.f + __expf(-2.f * x)) - 1.f;
}
__device__ __forceinline__ unsigned short f2bf(float x) {
  unsigned int u = __float_as_uint(x);
  unsigned int r = u + 0x7fffu + ((u >> 16) & 1u);
  return (unsigned short)(r >> 16);
}
__device__ __forceinline__ unsigned int packbf(float lo, float hi) {
  return (unsigned int)f2bf(lo) | ((unsigned int)f2bf(hi) << 16);
}
__device__ __forceinline__ float bf_lo(unsigned int u) {
  return __uint_as_float(u << 16);
}
__device__ __forceinline__ float bf_hi(unsigned int u) {
  return __uint_as_float(u & 0xffff0000u);
}
__device__ __forceinline__ float bf2f(unsigned short u) {
  return __uint_as_float((unsigned int)u << 16);
}

// ---------------- K1: h(bf16) = xf @ lin_w.T; 2 channels/thread ------------
__global__ __launch_bounds__(576) void k_lin(const float* __restrict__ xf,
                                             const float* __restrict__ lin_w,
                                             unsigned int* __restrict__ hbf,
                                             int N) {
  int tid = threadIdx.x;
  float w0[24], w1[24];
  const float* wr = lin_w + (size_t)(2 * tid) * GAT_IN;
#pragma unroll
  for (int j = 0; j < 24; ++j) {
    w0[j] = wr[j];
    w1[j] = wr[24 + j];
  }
  int n0 = blockIdx.x * LIN_CHUNK;
  int n1 = min(n0 + LIN_CHUNK, N);
  for (int n = n0; n < n1; ++n) {
    const float* xr = xf + (size_t)n * GAT_IN;
    float a0 = 0.f, a1 = 0.f;
#pragma unroll
    for (int j = 0; j < 24; ++j) {
      float xv = xr[j];
      a0 += xv * w0[j];
      a1 += xv * w1[j];
    }
    hbf[(size_t)n * 576 + tid] = packbf(a0, a1);
  }
}

// ---------------- K2a: v_src/v_dst[3][24] = att @ W (fold) -----------------
__global__ __launch_bounds__(64) void k_prep(const float* __restrict__ lin_w,
                                             const float* __restrict__ att_src,
                                             const float* __restrict__ att_dst,
                                             float* __restrict__ vbuf) {
  int b = blockIdx.x;  // 0..71
  int h = b / 24, j = b % 24;
  int lane = threadIdx.x;
  float as = 0.f, ad = 0.f;
  for (int c = lane; c < C_OUT; c += 64) {
    float wv = lin_w[(size_t)(h * C_OUT + c) * GAT_IN + j];
    as += att_src[h * C_OUT + c] * wv;
    ad += att_dst[h * C_OUT + c] * wv;
  }
#pragma unroll
  for (int off = 32; off >= 1; off >>= 1) {
    as += __shfl_xor(as, off, 64);
    ad += __shfl_xor(ad, off, 64);
  }
  if (lane == 0) {
    vbuf[h * 24 + j] = as;
    vbuf[72 + h * 24 + j] = ad;
  }
}

// ---------------- K2b: a_src/a_dst = xf @ v.T ------------------------------
__global__ __launch_bounds__(256) void k_av(const float* __restrict__ xf,
                                            const float* __restrict__ vbuf,
                                            float* __restrict__ a_src,
                                            float* __restrict__ a_dst, int N) {
  __shared__ float s_v[144];
  int tid = threadIdx.x;
  if (tid < 144) s_v[tid] = vbuf[tid];
  __syncthreads();
  int n = blockIdx.x * 256 + tid;
  if (n >= N) return;
  float xv[24];
  const float4* xr = (const float4*)(xf + (size_t)n * GAT_IN);
#pragma unroll
  for (int q = 0; q < 6; ++q) {
    float4 t = xr[q];
    xv[4 * q] = t.x; xv[4 * q + 1] = t.y; xv[4 * q + 2] = t.z; xv[4 * q + 3] = t.w;
  }
#pragma unroll
  for (int h = 0; h < 3; ++h) {
    float as = 0.f, ad = 0.f;
#pragma unroll
    for (int j = 0; j < 24; ++j) {
      as += xv[j] * s_v[h * 24 + j];
      ad += xv[j] * s_v[72 + h * 24 + j];
    }
    a_src[n * 3 + h] = as;
    a_dst[n * 3 + h] = ad;
  }
}

// ---------------- CSR build ------------------------------------------------
__global__ void k_count(const int* __restrict__ edst, int* __restrict__ deg,
                        int E, int ET) {
  int e = blockIdx.x * blockDim.x + threadIdx.x;
  if (e >= ET) return;
  int d = (e < E) ? edst[e] : (e - E);
  atomicAdd(&deg[d], 1);
}

__global__ __launch_bounds__(1024) void k_scan(const int* __restrict__ deg,
                                               int* __restrict__ rowptr,
                                               int* __restrict__ cursor,
                                               int n) {
  __shared__ int s_wt[16];
  int tid = threadIdx.x, lane = tid & 63, w = tid >> 6;
  int carry = 0;
  for (int base = 0; base < n; base += 4096) {
    int idx = base + tid * 4;
    int v0 = (idx + 0 < n) ? deg[idx + 0] : 0;
    int v1 = (idx + 1 < n) ? deg[idx + 1] : 0;
    int v2 = (idx + 2 < n) ? deg[idx + 2] : 0;
    int v3 = (idx + 3 < n) ? deg[idx + 3] : 0;
    int s1 = v0 + v1, s2 = s1 + v2, s3 = s2 + v3;
    int v = s3;
#pragma unroll
    for (int off = 1; off < 64; off <<= 1) {
      int t = __shfl_up(v, off, 64);
      if (lane >= off) v += t;
    }
    if (lane == 63) s_wt[w] = v;
    __syncthreads();
    if (w == 0) {
      int x = (lane < 16) ? s_wt[lane] : 0;
#pragma unroll
      for (int off = 1; off < 16; off <<= 1) {
        int t = __shfl_up(x, off, 64);
        if (lane >= off) x += t;
      }
      if (lane < 16) s_wt[lane] = x;
    }
    __syncthreads();
    int wexcl = (w == 0) ? 0 : s_wt[w - 1];
    int total = s_wt[15];
    int excl = carry + wexcl + v - s3;
    if (idx + 0 < n) { rowptr[idx + 0] = excl;      cursor[idx + 0] = excl; }
    if (idx + 1 < n) { rowptr[idx + 1] = excl + v0; cursor[idx + 1] = excl + v0; }
    if (idx + 2 < n) { rowptr[idx + 2] = excl + s1; cursor[idx + 2] = excl + s1; }
    if (idx + 3 < n) { rowptr[idx + 3] = excl + s2; cursor[idx + 3] = excl + s2; }
    carry += total;
    __syncthreads();
  }
  if (tid == 0) rowptr[n] = carry;
}

__global__ void k_scatter(const int* __restrict__ edst,
                          int* __restrict__ cursor, int* __restrict__ elist,
                          int E, int ET) {
  int e = blockIdx.x * blockDim.x + threadIdx.x;
  if (e >= ET) return;
  int d = (e < E) ? edst[e] : (e - E);
  int pos = atomicAdd(&cursor[d], 1);
  elist[pos] = e;
}

// ---------------- K6: edge softmax + bf16 gather aggregation ---------------
__device__ __forceinline__ float lrelu(float x) {
  return x >= 0.f ? x : NEG_SLOPE * x;
}

__global__ __launch_bounds__(192) void k_agg(
    const unsigned int* __restrict__ hbf, const float* __restrict__ a_src,
    const float* __restrict__ a_dst, const int* __restrict__ esrc,
    const int* __restrict__ elist, const int* __restrict__ rowptr,
    const float* __restrict__ gat_bias, float* __restrict__ gat_out, int E,
    int N) {
  __shared__ int s_src[CAP];
  __shared__ float s_w[CAP * 3];
  __shared__ float wred[3][3];
  __shared__ float s_sc[6];
  int n = blockIdx.x;
  int tid = threadIdx.x, lane = tid & 63, wv = tid >> 6;
  int start = rowptr[n], deg = rowptr[n + 1] - start;
  float ad0 = a_dst[n * 3 + 0], ad1 = a_dst[n * 3 + 1], ad2 = a_dst[n * 3 + 2];
  bool cached = (deg <= CAP);

  // pass 1: alphas + max
  float m0 = -1e30f, m1 = -1e30f, m2 = -1e30f;
  for (int i = tid; i < deg; i += 192) {
    int e = elist[start + i];
    int s = (e < E) ? esrc[e] : (e - E);
    float x0 = lrelu(a_src[s * 3 + 0] + ad0);
    float x1 = lrelu(a_src[s * 3 + 1] + ad1);
    float x2 = lrelu(a_src[s * 3 + 2] + ad2);
    if (cached) {
      s_src[i] = s;
      s_w[i * 3] = x0; s_w[i * 3 + 1] = x1; s_w[i * 3 + 2] = x2;
    }
    m0 = fmaxf(m0, x0); m1 = fmaxf(m1, x1); m2 = fmaxf(m2, x2);
  }
#pragma unroll
  for (int off = 32; off >= 1; off >>= 1) {
    m0 = fmaxf(m0, __shfl_xor(m0, off, 64));
    m1 = fmaxf(m1, __shfl_xor(m1, off, 64));
    m2 = fmaxf(m2, __shfl_xor(m2, off, 64));
  }
  if (lane == 0) { wred[wv][0] = m0; wred[wv][1] = m1; wred[wv][2] = m2; }
  __syncthreads();
  if (tid < 3) {
    float m = fmaxf(fmaxf(wred[0][tid], wred[1][tid]), wred[2][tid]);
    s_sc[tid] = m;
  }
  __syncthreads();
  m0 = s_sc[0]; m1 = s_sc[1]; m2 = s_sc[2];

  // pass 2: exp + denom
  float t0 = 0.f, t1 = 0.f, t2 = 0.f;
  for (int i = tid; i < deg; i += 192) {
    float x0, x1, x2;
    if (cached) {
      x0 = s_w[i * 3]; x1 = s_w[i * 3 + 1]; x2 = s_w[i * 3 + 2];
    } else {
      int e = elist[start + i];
      int s = (e < E) ? esrc[e] : (e - E);
      x0 = lrelu(a_src[s * 3 + 0] + ad0);
      x1 = lrelu(a_src[s * 3 + 1] + ad1);
      x2 = lrelu(a_src[s * 3 + 2] + ad2);
    }
    float e0 = expf(x0 - m0), e1 = expf(x1 - m1), e2 = expf(x2 - m2);
    if (cached) { s_w[i * 3] = e0; s_w[i * 3 + 1] = e1; s_w[i * 3 + 2] = e2; }
    t0 += e0; t1 += e1; t2 += e2;
  }
#pragma unroll
  for (int off = 32; off >= 1; off >>= 1) {
    t0 += __shfl_xor(t0, off, 64);
    t1 += __shfl_xor(t1, off, 64);
    t2 += __shfl_xor(t2, off, 64);
  }
  if (lane == 0) { wred[wv][0] = t0; wred[wv][1] = t1; wred[wv][2] = t2; }
  __syncthreads();
  if (tid < 3) {
    float ssum = wred[0][tid] + wred[1][tid] + wred[2][tid];
    s_sc[3 + tid] = 1.0f / ssum;
  }
  __syncthreads();
  float inv0 = s_sc[3], inv1 = s_sc[4], inv2 = s_sc[5];

  // pass 3: bf16 gather, 2 channels (1 uint) per thread per head
  float2 acc0 = {0.f, 0.f}, acc1 = {0.f, 0.f}, acc2 = {0.f, 0.f};
  if (cached) {
#pragma unroll 4
    for (int i = 0; i < deg; ++i) {
      int s = s_src[i];
      const unsigned int* hr = hbf + (size_t)s * 576;
      float w0 = s_w[i * 3] * inv0;
      float w1 = s_w[i * 3 + 1] * inv1;
      float w2 = s_w[i * 3 + 2] * inv2;
      unsigned int u0 = hr[tid];
      unsigned int u1 = hr[192 + tid];
      unsigned int u2 = hr[384 + tid];
      acc0.x += w0 * bf_lo(u0); acc0.y += w0 * bf_hi(u0);
      acc1.x += w1 * bf_lo(u1); acc1.y += w1 * bf_hi(u1);
      acc2.x += w2 * bf_lo(u2); acc2.y += w2 * bf_hi(u2);
    }
  } else {
    for (int i = 0; i < deg; ++i) {
      int e = elist[start + i];
      int s = (e < E) ? esrc[e] : (e - E);
      float x0 = lrelu(a_src[s * 3 + 0] + ad0);
      float x1 = lrelu(a_src[s * 3 + 1] + ad1);
      float x2 = lrelu(a_src[s * 3 + 2] + ad2);
      float w0 = expf(x0 - m0) * inv0;
      float w1 = expf(x1 - m1) * inv1;
      float w2 = expf(x2 - m2) * inv2;
      const unsigned int* hr = hbf + (size_t)s * 576;
      unsigned int u0 = hr[tid];
      unsigned int u1 = hr[192 + tid];
      unsigned int u2 = hr[384 + tid];
      acc0.x += w0 * bf_lo(u0); acc0.y += w0 * bf_hi(u0);
      acc1.x += w1 * bf_lo(u1); acc1.y += w1 * bf_hi(u1);
      acc2.x += w2 * bf_lo(u2); acc2.y += w2 * bf_hi(u2);
    }
  }
  float2 o;
  o.x = (acc0.x + acc1.x + acc2.x) * (1.f / 3.f) + gat_bias[2 * tid];
  o.y = (acc0.y + acc1.y + acc2.y) * (1.f / 3.f) + gat_bias[2 * tid + 1];
  *(float2*)&gat_out[(size_t)n * C_OUT + 2 * tid] = o;
}

// ---------------- K7a: gi(bf16) = gat @ w_ih.T + b_ih ----------------------
__global__ __launch_bounds__(128) void k_gi(const float* __restrict__ A,
                                            const float* __restrict__ wih,
                                            const float* __restrict__ bih,
                                            unsigned int* __restrict__ gi,
                                            int R) {
  __shared__ float At[32][68];
  __shared__ float Bt[32][100];
  __shared__ float s_bias[96];
  int tid = threadIdx.x;
  int row0 = blockIdx.x * 64;
  {
    int r = tid >> 3;
    int kq = (tid & 7) * 4;
    for (int rr = 0; rr < 64; rr += 16) {
      int row = row0 + rr + r;
      int rc = min(row, R - 1);
      float4 a = *(const float4*)(A + (size_t)rc * 32 + kq);
      At[kq + 0][rr + r] = a.x;
      At[kq + 1][rr + r] = a.y;
      At[kq + 2][rr + r] = a.z;
      At[kq + 3][rr + r] = a.w;
    }
  }
#pragma unroll
  for (int q = 0; q < 6; ++q) {
    int fid = q * 128 + tid;
    int c = fid >> 3;
    int k4 = (fid & 7) * 4;
    float4 b = *(const float4*)(wih + (size_t)c * 32 + k4);
    Bt[k4 + 0][c] = b.x;
    Bt[k4 + 1][c] = b.y;
    Bt[k4 + 2][c] = b.z;
    Bt[k4 + 3][c] = b.w;
  }
  if (tid < 96) s_bias[tid] = bih[tid];
  __syncthreads();
  int rowg = tid & 7;
  int colg = tid >> 3;
  int r0 = rowg * 8, c0 = colg * 6;
  float acc[8][6];
#pragma unroll
  for (int i = 0; i < 8; ++i)
#pragma unroll
    for (int j = 0; j < 6; ++j) acc[i][j] = 0.f;
#pragma unroll 4
  for (int k = 0; k < 32; ++k) {
    float4 a0 = *(const float4*)&At[k][r0];
    float4 a1 = *(const float4*)&At[k][r0 + 4];
    float b[6];
#pragma unroll
    for (int j = 0; j < 6; ++j) b[j] = Bt[k][c0 + j];
    float av[8] = {a0.x, a0.y, a0.z, a0.w, a1.x, a1.y, a1.z, a1.w};
#pragma unroll
    for (int i = 0; i < 8; ++i)
#pragma unroll
      for (int j = 0; j < 6; ++j) acc[i][j] += av[i] * b[j];
  }
#pragma unroll
  for (int i = 0; i < 8; ++i) {
    int row = row0 + r0 + i;
    if (row < R) {
      unsigned int* crow = gi + (size_t)row * 48 + (c0 >> 1);
#pragma unroll
      for (int jj = 0; jj < 3; ++jj) {
        float lo = acc[i][2 * jj] + s_bias[c0 + 2 * jj];
        float hi = acc[i][2 * jj + 1] + s_bias[c0 + 2 * jj + 1];
        crow[jj] = packbf(lo, hi);
      }
    }
  }
}

// ---------------- K7b: GRU recurrence + projections ------------------------
__global__ __launch_bounds__(256) void k_rec(
    const unsigned short* __restrict__ gi, const float* __restrict__ whh,
    const float* __restrict__ bhh, const float* __restrict__ p1w,
    const float* __restrict__ p1b, const float* __restrict__ p2w,
    const float* __restrict__ p2b, float* __restrict__ out, int N) {
  __shared__ float h_hist[8][13][36];
  __shared__ float s_o[8][12];
  int tid = threadIdx.x;
  int nd = tid >> 5;
  int k = tid & 31;
  int node = blockIdx.x * 8 + nd;
  if (node >= N) return;  // no barriers below -> safe

  float wr[32], wz[32], wn[32];
  {
    const float4* pr = (const float4*)(whh + (size_t)k * HID);
    const float4* pz = (const float4*)(whh + (size_t)(HID + k) * HID);
    const float4* pn = (const float4*)(whh + (size_t)(2 * HID + k) * HID);
#pragma unroll
    for (int j = 0; j < 8; ++j) {
      float4 a = pr[j], b = pz[j], c = pn[j];
      wr[4 * j] = a.x; wr[4 * j + 1] = a.y; wr[4 * j + 2] = a.z; wr[4 * j + 3] = a.w;
      wz[4 * j] = b.x; wz[4 * j + 1] = b.y; wz[4 * j + 2] = b.z; wz[4 * j + 3] = b.w;
      wn[4 * j] = c.x; wn[4 * j + 1] = c.y; wn[4 * j + 2] = c.z; wn[4 * j + 3] = c.w;
    }
  }
  float bhr = bhh[k], bhz = bhh[HID + k], bhn = bhh[2 * HID + k];
  h_hist[nd][0][k] = 0.f;
  float h = 0.f;
  const unsigned short* girow = gi + (size_t)node * TSTEPS * 96;
  for (int t = 0; t < TSTEPS; ++t) {
    float gr = bf2f(girow[t * 96 + k]);
    float gz = bf2f(girow[t * 96 + 32 + k]);
    float gn = bf2f(girow[t * 96 + 64 + k]);
    float ar = 0.f, az = 0.f, an = 0.f;
    const float* hh = &h_hist[nd][t][0];
#pragma unroll
    for (int q = 0; q < 8; ++q) {
      float4 hp = *(const float4*)(hh + q * 4);
      ar += wr[4 * q] * hp.x + wr[4 * q + 1] * hp.y + wr[4 * q + 2] * hp.z +
            wr[4 * q + 3] * hp.w;
      az += wz[4 * q] * hp.x + wz[4 * q + 1] * hp.y + wz[4 * q + 2] * hp.z +
            wz[4 * q + 3] * hp.w;
      an += wn[4 * q] * hp.x + wn[4 * q + 1] * hp.y + wn[4 * q + 2] * hp.z +
            wn[4 * q + 3] * hp.w;
    }
    float r = sigm(gr + ar + bhr);
    float z = sigm(gz + az + bhz);
    float nn = tanh_fast(gn + r * (an + bhn));
    float hnew = (1.f - z) * nn + z * h;
    h = hnew;
    h_hist[nd][t + 1][k] = hnew;
  }
  if (k < TSTEPS) {
    float o = p1b[0];
#pragma unroll
    for (int kk = 0; kk < HID; ++kk) o += h_hist[nd][k + 1][kk] * p1w[kk];
    s_o[nd][k] = o;
  }
  if (k < TSTEPS) {
    float acc = p2b[k];
#pragma unroll
    for (int s2 = 0; s2 < TSTEPS; ++s2)
      acc += p2w[k * TSTEPS + s2] * s_o[nd][s2];
    out[(size_t)node * TSTEPS + k] = acc;
  }
}

// ---------------------------------------------------------------------------
extern "C" void kernel_launch(void* const* d_in, const int* in_sizes, int n_in,
                              void* d_out, int out_size, void* d_ws,
                              size_t ws_size, hipStream_t stream) {
  const float* x = (const float*)d_in[0];
  const int* ei = (const int*)d_in[1];
  const float* lin_w = (const float*)d_in[2];
  const float* att_src = (const float*)d_in[3];
  const float* att_dst = (const float*)d_in[4];
  const float* gat_bias = (const float*)d_in[5];
  const float* w_ih = (const float*)d_in[6];
  const float* w_hh = (const float*)d_in[7];
  const float* b_ih = (const float*)d_in[8];
  const float* b_hh = (const float*)d_in[9];
  const float* p1w = (const float*)d_in[10];
  const float* p1b = (const float*)d_in[11];
  const float* p2w = (const float*)d_in[12];
  const float* p2b = (const float*)d_in[13];

  int N = in_sizes[0] / GAT_IN;  // 10000
  int E = in_sizes[1] / 2;       // 160000
  int ET = E + N;
  int R = N * TSTEPS;            // 120000

  size_t off = 0;
  char* base = (char*)d_ws;
  auto alloc = [&](size_t bytes) {
    void* p = base + off;
    off += (bytes + 255) & ~(size_t)255;
    return p;
  };
  unsigned int* hbf = (unsigned int*)alloc((size_t)N * 576 * 4);  // bf16 h; reused as gi
  float* gatb = (float*)alloc((size_t)N * C_OUT * 4);
  float* a_srcb = (float*)alloc((size_t)N * 3 * 4);
  float* a_dstb = (float*)alloc((size_t)N * 3 * 4);
  float* vbuf = (float*)alloc(144 * 4);
  int* deg = (int*)alloc((size_t)N * 4);
  int* rowptr = (int*)alloc((size_t)(N + 1) * 4);
  int* cursor = (int*)alloc((size_t)N * 4);
  int* elist = (int*)alloc((size_t)ET * 4);
  unsigned int* gib = hbf;  // alias: hbf dead after k_agg; gi = N*12*48 uints
  (void)ws_size; (void)n_in; (void)out_size;

  hipMemsetAsync(deg, 0, (size_t)N * 4, stream);

  k_count<<<(ET + 255) / 256, 256, 0, stream>>>(ei + E, deg, E, ET);
  k_scan<<<1, 1024, 0, stream>>>(deg, rowptr, cursor, N);
  k_scatter<<<(ET + 255) / 256, 256, 0, stream>>>(ei + E, cursor, elist, E, ET);
  k_prep<<<72, 64, 0, stream>>>(lin_w, att_src, att_dst, vbuf);
  k_av<<<(N + 255) / 256, 256, 0, stream>>>(x, vbuf, a_srcb, a_dstb, N);
  k_lin<<<(N + LIN_CHUNK - 1) / LIN_CHUNK, 576, 0, stream>>>(x, lin_w, hbf, N);
  k_agg<<<N, 192, 0, stream>>>(hbf, a_srcb, a_dstb, ei, elist, rowptr,
                               gat_bias, gatb, E, N);
  k_gi<<<(R + 63) / 64, 128, 0, stream>>>(gatb, w_ih, b_ih, gib, R);
  k_rec<<<(N + 7) / 8, 256, 0, stream>>>((const unsigned short*)gib, w_hh,
                                         b_hh, p1w, p1b, p2w, p2b,
                                         (float*)d_out, N);
}

// Round 4
// 186.287 us; speedup vs baseline: 1.8358x; 1.0201x over previous
//
#include <hip/hip_runtime.h>
#include <math.h>

#define HEADS 3
#define C_OUT 384
#define GAT_IN 24
#define HID 32
#define TSTEPS 12
#define NEG_SLOPE 0.2f
#define CAP 64
#define LIN_CHUNK 25

__device__ __forceinline__ float sigm(float x) {
  return 1.f / (1.f + __expf(-x));
}
__device__ __forceinline__ float tanh_fast(float x) {
  return 2.f / (1.f + __expf(-2.f * x)) - 1.f;
}
__device__ __forceinline__ unsigned short f2bf(float x) {
  unsigned int u = __float_as_uint(x);
  unsigned int r = u + 0x7fffu + ((u >> 16) & 1u);
  return (unsigned short)(r >> 16);
}
__device__ __forceinline__ unsigned int packbf(float lo, float hi) {
  return (unsigned int)f2bf(lo) | ((unsigned int)f2bf(hi) << 16);
}
__device__ __forceinline__ float bf_lo(unsigned int u) {
  return __uint_as_float(u << 16);
}
__device__ __forceinline__ float bf_hi(unsigned int u) {
  return __uint_as_float(u & 0xffff0000u);
}
__device__ __forceinline__ float bf2f(unsigned short u) {
  return __uint_as_float((unsigned int)u << 16);
}
__device__ __forceinline__ float lrelu(float x) {
  return x >= 0.f ? x : NEG_SLOPE * x;
}

// ---------------- K1: h(bf16) = xf @ lin_w.T; 2 channels/thread ------------
__global__ __launch_bounds__(576) void k_lin(const float* __restrict__ xf,
                                             const float* __restrict__ lin_w,
                                             unsigned int* __restrict__ hbf,
                                             int N) {
  int tid = threadIdx.x;
  float w0[24], w1[24];
  const float* wr = lin_w + (size_t)(2 * tid) * GAT_IN;
#pragma unroll
  for (int j = 0; j < 24; ++j) {
    w0[j] = wr[j];
    w1[j] = wr[24 + j];
  }
  int n0 = blockIdx.x * LIN_CHUNK;
  int n1 = min(n0 + LIN_CHUNK, N);
  for (int n = n0; n < n1; ++n) {
    const float* xr = xf + (size_t)n * GAT_IN;
    float a0 = 0.f, a1 = 0.f;
#pragma unroll
    for (int j = 0; j < 24; ++j) {
      float xv = xr[j];
      a0 += xv * w0[j];
      a1 += xv * w1[j];
    }
    hbf[(size_t)n * 576 + tid] = packbf(a0, a1);
  }
}

// ---------------- K2a: v_src/v_dst[3][24] = att @ W (fold) -----------------
__global__ __launch_bounds__(64) void k_prep(const float* __restrict__ lin_w,
                                             const float* __restrict__ att_src,
                                             const float* __restrict__ att_dst,
                                             float* __restrict__ vbuf) {
  int b = blockIdx.x;  // 0..71
  int h = b / 24, j = b % 24;
  int lane = threadIdx.x;
  float as = 0.f, ad = 0.f;
  for (int c = lane; c < C_OUT; c += 64) {
    float wv = lin_w[(size_t)(h * C_OUT + c) * GAT_IN + j];
    as += att_src[h * C_OUT + c] * wv;
    ad += att_dst[h * C_OUT + c] * wv;
  }
#pragma unroll
  for (int off = 32; off >= 1; off >>= 1) {
    as += __shfl_xor(as, off, 64);
    ad += __shfl_xor(ad, off, 64);
  }
  if (lane == 0) {
    vbuf[h * 24 + j] = as;
    vbuf[72 + h * 24 + j] = ad;
  }
}

// ---------------- K2b: a_src/a_dst = xf @ v.T ------------------------------
__global__ __launch_bounds__(256) void k_av(const float* __restrict__ xf,
                                            const float* __restrict__ vbuf,
                                            float* __restrict__ a_src,
                                            float* __restrict__ a_dst, int N) {
  __shared__ float s_v[144];
  int tid = threadIdx.x;
  if (tid < 144) s_v[tid] = vbuf[tid];
  __syncthreads();
  int n = blockIdx.x * 256 + tid;
  if (n >= N) return;
  float xv[24];
  const float4* xr = (const float4*)(xf + (size_t)n * GAT_IN);
#pragma unroll
  for (int q = 0; q < 6; ++q) {
    float4 t = xr[q];
    xv[4 * q] = t.x; xv[4 * q + 1] = t.y; xv[4 * q + 2] = t.z; xv[4 * q + 3] = t.w;
  }
#pragma unroll
  for (int h = 0; h < 3; ++h) {
    float as = 0.f, ad = 0.f;
#pragma unroll
    for (int j = 0; j < 24; ++j) {
      as += xv[j] * s_v[h * 24 + j];
      ad += xv[j] * s_v[72 + h * 24 + j];
    }
    a_src[n * 3 + h] = as;
    a_dst[n * 3 + h] = ad;
  }
}

// ---------------- CSR build ------------------------------------------------
__global__ void k_count(const int* __restrict__ edst, int* __restrict__ deg,
                        int E, int ET) {
  int e = blockIdx.x * blockDim.x + threadIdx.x;
  if (e >= ET) return;
  int d = (e < E) ? edst[e] : (e - E);
  atomicAdd(&deg[d], 1);
}

__global__ __launch_bounds__(1024) void k_scan(const int* __restrict__ deg,
                                               int* __restrict__ rowptr,
                                               int* __restrict__ cursor,
                                               int n) {
  __shared__ int s_wt[16];
  int tid = threadIdx.x, lane = tid & 63, w = tid >> 6;
  int carry = 0;
  for (int base = 0; base < n; base += 4096) {
    int idx = base + tid * 4;
    int v0 = (idx + 0 < n) ? deg[idx + 0] : 0;
    int v1 = (idx + 1 < n) ? deg[idx + 1] : 0;
    int v2 = (idx + 2 < n) ? deg[idx + 2] : 0;
    int v3 = (idx + 3 < n) ? deg[idx + 3] : 0;
    int s1 = v0 + v1, s2 = s1 + v2, s3 = s2 + v3;
    int v = s3;
#pragma unroll
    for (int off = 1; off < 64; off <<= 1) {
      int t = __shfl_up(v, off, 64);
      if (lane >= off) v += t;
    }
    if (lane == 63) s_wt[w] = v;
    __syncthreads();
    if (w == 0) {
      int x = (lane < 16) ? s_wt[lane] : 0;
#pragma unroll
      for (int off = 1; off < 16; off <<= 1) {
        int t = __shfl_up(x, off, 64);
        if (lane >= off) x += t;
      }
      if (lane < 16) s_wt[lane] = x;
    }
    __syncthreads();
    int wexcl = (w == 0) ? 0 : s_wt[w - 1];
    int total = s_wt[15];
    int excl = carry + wexcl + v - s3;
    if (idx + 0 < n) { rowptr[idx + 0] = excl;      cursor[idx + 0] = excl; }
    if (idx + 1 < n) { rowptr[idx + 1] = excl + v0; cursor[idx + 1] = excl + v0; }
    if (idx + 2 < n) { rowptr[idx + 2] = excl + s1; cursor[idx + 2] = excl + s1; }
    if (idx + 3 < n) { rowptr[idx + 3] = excl + s2; cursor[idx + 3] = excl + s2; }
    carry += total;
    __syncthreads();
  }
  if (tid == 0) rowptr[n] = carry;
}

// scatter stores SRC id directly (drops one random gather from k_agg)
__global__ void k_scatter(const int* __restrict__ esrc,
                          const int* __restrict__ edst,
                          int* __restrict__ cursor, int* __restrict__ slist,
                          int E, int ET) {
  int e = blockIdx.x * blockDim.x + threadIdx.x;
  if (e >= ET) return;
  int d, s;
  if (e < E) { d = edst[e]; s = esrc[e]; }
  else { d = e - E; s = e - E; }
  int pos = atomicAdd(&cursor[d], 1);
  slist[pos] = s;
}

// ---------------- K6: edge softmax (no-max) + bf16 gather ------------------
// 256 threads = 4 edge-lanes (waves) x 64 channel-threads.
__global__ __launch_bounds__(256) void k_agg(
    const unsigned int* __restrict__ hbf, const float* __restrict__ a_src,
    const float* __restrict__ a_dst, const int* __restrict__ slist,
    const int* __restrict__ rowptr, const float* __restrict__ gat_bias,
    unsigned int* __restrict__ gatbf, int N) {
  __shared__ int s_src[CAP];
  __shared__ float s_w[CAP * 3];
  __shared__ float s_red[3][64][19];
  __shared__ float wred[4][3];
  __shared__ float s_inv[3];
  int n = blockIdx.x;
  int tid = threadIdx.x, lane = tid & 63, wv = tid >> 6;
  int start = rowptr[n], deg = rowptr[n + 1] - start;
  float ad0 = a_dst[n * 3 + 0], ad1 = a_dst[n * 3 + 1], ad2 = a_dst[n * 3 + 2];
  bool cached = (deg <= CAP);

  // pass A: exp(alpha) + sum (logits bounded ~|1| => no max-shift needed;
  // exp(a)/sum(exp(a)) is mathematically identical to the shifted form)
  float t0 = 0.f, t1 = 0.f, t2 = 0.f;
  for (int i = tid; i < deg; i += 256) {
    int s = slist[start + i];
    float e0 = __expf(lrelu(a_src[s * 3 + 0] + ad0));
    float e1 = __expf(lrelu(a_src[s * 3 + 1] + ad1));
    float e2 = __expf(lrelu(a_src[s * 3 + 2] + ad2));
    if (cached) {
      s_src[i] = s;
      s_w[i * 3] = e0; s_w[i * 3 + 1] = e1; s_w[i * 3 + 2] = e2;
    }
    t0 += e0; t1 += e1; t2 += e2;
  }
#pragma unroll
  for (int off = 32; off >= 1; off >>= 1) {
    t0 += __shfl_xor(t0, off, 64);
    t1 += __shfl_xor(t1, off, 64);
    t2 += __shfl_xor(t2, off, 64);
  }
  if (lane == 0) { wred[wv][0] = t0; wred[wv][1] = t1; wred[wv][2] = t2; }
  __syncthreads();
  if (tid < 3) {
    float ssum = wred[0][tid] + wred[1][tid] + wred[2][tid] + wred[3][tid];
    s_inv[tid] = 1.0f / ssum;
  }
  __syncthreads();
  float inv0 = s_inv[0], inv1 = s_inv[1], inv2 = s_inv[2];

  // pass B: 4 edges in flight (one per wave), 9 coalesced b32 loads/edge/thr
  int el = wv;      // edge lane (wave-uniform)
  int ch = lane;    // channel thread
  float acc[3][3][2];
#pragma unroll
  for (int h = 0; h < 3; ++h)
#pragma unroll
    for (int p = 0; p < 3; ++p) { acc[h][p][0] = 0.f; acc[h][p][1] = 0.f; }

  if (cached) {
#pragma unroll 2
    for (int base = 0; base < deg; base += 4) {
      int i = base + el;
      if (i < deg) {  // wave-uniform branch
        int s = s_src[i];
        const unsigned int* hr = hbf + (size_t)s * 576;
        float w0 = s_w[i * 3] * inv0;
        float w1 = s_w[i * 3 + 1] * inv1;
        float w2 = s_w[i * 3 + 2] * inv2;
        float wt[3] = {w0, w1, w2};
#pragma unroll
        for (int h = 0; h < 3; ++h) {
          unsigned int ua = hr[h * 192 + ch];
          unsigned int ub = hr[h * 192 + 64 + ch];
          unsigned int uc = hr[h * 192 + 128 + ch];
          float w = wt[h];
          acc[h][0][0] += w * bf_lo(ua); acc[h][0][1] += w * bf_hi(ua);
          acc[h][1][0] += w * bf_lo(ub); acc[h][1][1] += w * bf_hi(ub);
          acc[h][2][0] += w * bf_lo(uc); acc[h][2][1] += w * bf_hi(uc);
        }
      }
    }
  } else {
    for (int base = 0; base < deg; base += 4) {
      int i = base + el;
      if (i < deg) {
        int s = slist[start + i];
        float w0 = __expf(lrelu(a_src[s * 3 + 0] + ad0)) * inv0;
        float w1 = __expf(lrelu(a_src[s * 3 + 1] + ad1)) * inv1;
        float w2 = __expf(lrelu(a_src[s * 3 + 2] + ad2)) * inv2;
        float wt[3] = {w0, w1, w2};
        const unsigned int* hr = hbf + (size_t)s * 576;
#pragma unroll
        for (int h = 0; h < 3; ++h) {
          unsigned int ua = hr[h * 192 + ch];
          unsigned int ub = hr[h * 192 + 64 + ch];
          unsigned int uc = hr[h * 192 + 128 + ch];
          float w = wt[h];
          acc[h][0][0] += w * bf_lo(ua); acc[h][0][1] += w * bf_hi(ua);
          acc[h][1][0] += w * bf_lo(ub); acc[h][1][1] += w * bf_hi(ub);
          acc[h][2][0] += w * bf_lo(uc); acc[h][2][1] += w * bf_hi(uc);
        }
      }
    }
  }
  // cross-wave reduction
  if (wv > 0) {
    float* dst = &s_red[wv - 1][ch][0];
#pragma unroll
    for (int h = 0; h < 3; ++h)
#pragma unroll
      for (int p = 0; p < 3; ++p) {
        dst[h * 6 + p * 2 + 0] = acc[h][p][0];
        dst[h * 6 + p * 2 + 1] = acc[h][p][1];
      }
  }
  __syncthreads();
  if (wv == 0) {
#pragma unroll
    for (int w = 0; w < 3; ++w) {
      const float* src = &s_red[w][ch][0];
#pragma unroll
      for (int h = 0; h < 3; ++h)
#pragma unroll
        for (int p = 0; p < 3; ++p) {
          acc[h][p][0] += src[h * 6 + p * 2 + 0];
          acc[h][p][1] += src[h * 6 + p * 2 + 1];
        }
    }
    const float2* b2 = (const float2*)gat_bias;
#pragma unroll
    for (int p = 0; p < 3; ++p) {
      int m = p * 64 + ch;
      float2 bb = b2[m];
      float lo = (acc[0][p][0] + acc[1][p][0] + acc[2][p][0]) * (1.f / 3.f) + bb.x;
      float hi = (acc[0][p][1] + acc[1][p][1] + acc[2][p][1]) * (1.f / 3.f) + bb.y;
      gatbf[(size_t)n * 192 + m] = packbf(lo, hi);
    }
  }
}

// ---------------- K7a: gi(bf16) = gat(bf16) @ w_ih.T + b_ih ----------------
__global__ __launch_bounds__(128) void k_gi(const unsigned int* __restrict__ A,
                                            const float* __restrict__ wih,
                                            const float* __restrict__ bih,
                                            unsigned int* __restrict__ gi,
                                            int R) {
  __shared__ float At[32][68];
  __shared__ float Bt[32][100];
  __shared__ float s_bias[96];
  int tid = threadIdx.x;
  int row0 = blockIdx.x * 64;
  {
    int r = tid >> 1;    // local row 0..63
    int half = tid & 1;  // which 16-k half
    int row = row0 + r;
    int rc = min(row, R - 1);
    const unsigned int* ar = A + (size_t)rc * 16 + half * 8;
    uint4 a0 = *(const uint4*)ar;
    uint4 a1 = *(const uint4*)(ar + 4);
    int k0 = half * 16;
    At[k0 + 0][r] = bf_lo(a0.x);  At[k0 + 1][r] = bf_hi(a0.x);
    At[k0 + 2][r] = bf_lo(a0.y);  At[k0 + 3][r] = bf_hi(a0.y);
    At[k0 + 4][r] = bf_lo(a0.z);  At[k0 + 5][r] = bf_hi(a0.z);
    At[k0 + 6][r] = bf_lo(a0.w);  At[k0 + 7][r] = bf_hi(a0.w);
    At[k0 + 8][r] = bf_lo(a1.x);  At[k0 + 9][r] = bf_hi(a1.x);
    At[k0 + 10][r] = bf_lo(a1.y); At[k0 + 11][r] = bf_hi(a1.y);
    At[k0 + 12][r] = bf_lo(a1.z); At[k0 + 13][r] = bf_hi(a1.z);
    At[k0 + 14][r] = bf_lo(a1.w); At[k0 + 15][r] = bf_hi(a1.w);
  }
#pragma unroll
  for (int q = 0; q < 6; ++q) {
    int fid = q * 128 + tid;
    int c = fid >> 3;
    int k4 = (fid & 7) * 4;
    float4 b = *(const float4*)(wih + (size_t)c * 32 + k4);
    Bt[k4 + 0][c] = b.x;
    Bt[k4 + 1][c] = b.y;
    Bt[k4 + 2][c] = b.z;
    Bt[k4 + 3][c] = b.w;
  }
  if (tid < 96) s_bias[tid] = bih[tid];
  __syncthreads();
  int rowg = tid & 7;
  int colg = tid >> 3;
  int r0 = rowg * 8, c0 = colg * 6;
  float acc[8][6];
#pragma unroll
  for (int i = 0; i < 8; ++i)
#pragma unroll
    for (int j = 0; j < 6; ++j) acc[i][j] = 0.f;
#pragma unroll 4
  for (int k = 0; k < 32; ++k) {
    float4 a0 = *(const float4*)&At[k][r0];
    float4 a1 = *(const float4*)&At[k][r0 + 4];
    float b[6];
#pragma unroll
    for (int j = 0; j < 6; ++j) b[j] = Bt[k][c0 + j];
    float av[8] = {a0.x, a0.y, a0.z, a0.w, a1.x, a1.y, a1.z, a1.w};
#pragma unroll
    for (int i = 0; i < 8; ++i)
#pragma unroll
      for (int j = 0; j < 6; ++j) acc[i][j] += av[i] * b[j];
  }
#pragma unroll
  for (int i = 0; i < 8; ++i) {
    int row = row0 + r0 + i;
    if (row < R) {
      unsigned int* crow = gi + (size_t)row * 48 + (c0 >> 1);
#pragma unroll
      for (int jj = 0; jj < 3; ++jj) {
        float lo = acc[i][2 * jj] + s_bias[c0 + 2 * jj];
        float hi = acc[i][2 * jj + 1] + s_bias[c0 + 2 * jj + 1];
        crow[jj] = packbf(lo, hi);
      }
    }
  }
}

// ---------------- K7b: GRU recurrence + projections ------------------------
__global__ __launch_bounds__(256) void k_rec(
    const unsigned short* __restrict__ gi, const float* __restrict__ whh,
    const float* __restrict__ bhh, const float* __restrict__ p1w,
    const float* __restrict__ p1b, const float* __restrict__ p2w,
    const float* __restrict__ p2b, float* __restrict__ out, int N) {
  __shared__ float h_hist[8][13][36];
  __shared__ float s_o[8][12];
  int tid = threadIdx.x;
  int nd = tid >> 5;
  int k = tid & 31;
  int node = blockIdx.x * 8 + nd;
  if (node >= N) return;  // no barriers below -> safe

  float wr[32], wz[32], wn[32];
  {
    const float4* pr = (const float4*)(whh + (size_t)k * HID);
    const float4* pz = (const float4*)(whh + (size_t)(HID + k) * HID);
    const float4* pn = (const float4*)(whh + (size_t)(2 * HID + k) * HID);
#pragma unroll
    for (int j = 0; j < 8; ++j) {
      float4 a = pr[j], b = pz[j], c = pn[j];
      wr[4 * j] = a.x; wr[4 * j + 1] = a.y; wr[4 * j + 2] = a.z; wr[4 * j + 3] = a.w;
      wz[4 * j] = b.x; wz[4 * j + 1] = b.y; wz[4 * j + 2] = b.z; wz[4 * j + 3] = b.w;
      wn[4 * j] = c.x; wn[4 * j + 1] = c.y; wn[4 * j + 2] = c.z; wn[4 * j + 3] = c.w;
    }
  }
  float bhr = bhh[k], bhz = bhh[HID + k], bhn = bhh[2 * HID + k];
  h_hist[nd][0][k] = 0.f;
  float h = 0.f;
  const unsigned short* girow = gi + (size_t)node * TSTEPS * 96;
  for (int t = 0; t < TSTEPS; ++t) {
    float gr = bf2f(girow[t * 96 + k]);
    float gz = bf2f(girow[t * 96 + 32 + k]);
    float gn = bf2f(girow[t * 96 + 64 + k]);
    float ar = 0.f, az = 0.f, an = 0.f;
    const float* hh = &h_hist[nd][t][0];
#pragma unroll
    for (int q = 0; q < 8; ++q) {
      float4 hp = *(const float4*)(hh + q * 4);
      ar += wr[4 * q] * hp.x + wr[4 * q + 1] * hp.y + wr[4 * q + 2] * hp.z +
            wr[4 * q + 3] * hp.w;
      az += wz[4 * q] * hp.x + wz[4 * q + 1] * hp.y + wz[4 * q + 2] * hp.z +
            wz[4 * q + 3] * hp.w;
      an += wn[4 * q] * hp.x + wn[4 * q + 1] * hp.y + wn[4 * q + 2] * hp.z +
            wn[4 * q + 3] * hp.w;
    }
    float r = sigm(gr + ar + bhr);
    float z = sigm(gz + az + bhz);
    float nn = tanh_fast(gn + r * (an + bhn));
    float hnew = (1.f - z) * nn + z * h;
    h = hnew;
    h_hist[nd][t + 1][k] = hnew;
  }
  if (k < TSTEPS) {
    float o = p1b[0];
#pragma unroll
    for (int kk = 0; kk < HID; ++kk) o += h_hist[nd][k + 1][kk] * p1w[kk];
    s_o[nd][k] = o;
  }
  if (k < TSTEPS) {
    float acc = p2b[k];
#pragma unroll
    for (int s2 = 0; s2 < TSTEPS; ++s2)
      acc += p2w[k * TSTEPS + s2] * s_o[nd][s2];
    out[(size_t)node * TSTEPS + k] = acc;
  }
}

// ---------------------------------------------------------------------------
extern "C" void kernel_launch(void* const* d_in, const int* in_sizes, int n_in,
                              void* d_out, int out_size, void* d_ws,
                              size_t ws_size, hipStream_t stream) {
  const float* x = (const float*)d_in[0];
  const int* ei = (const int*)d_in[1];
  const float* lin_w = (const float*)d_in[2];
  const float* att_src = (const float*)d_in[3];
  const float* att_dst = (const float*)d_in[4];
  const float* gat_bias = (const float*)d_in[5];
  const float* w_ih = (const float*)d_in[6];
  const float* w_hh = (const float*)d_in[7];
  const float* b_ih = (const float*)d_in[8];
  const float* b_hh = (const float*)d_in[9];
  const float* p1w = (const float*)d_in[10];
  const float* p1b = (const float*)d_in[11];
  const float* p2w = (const float*)d_in[12];
  const float* p2b = (const float*)d_in[13];

  int N = in_sizes[0] / GAT_IN;  // 10000
  int E = in_sizes[1] / 2;       // 160000
  int ET = E + N;
  int R = N * TSTEPS;            // 120000

  size_t off = 0;
  char* base = (char*)d_ws;
  auto alloc = [&](size_t bytes) {
    void* p = base + off;
    off += (bytes + 255) & ~(size_t)255;
    return p;
  };
  unsigned int* hbf = (unsigned int*)alloc((size_t)N * 576 * 4);  // bf16 h; reused as gi
  unsigned int* gatbf = (unsigned int*)alloc((size_t)N * 192 * 4);  // bf16 gat
  float* a_srcb = (float*)alloc((size_t)N * 3 * 4);
  float* a_dstb = (float*)alloc((size_t)N * 3 * 4);
  float* vbuf = (float*)alloc(144 * 4);
  int* deg = (int*)alloc((size_t)N * 4);
  int* rowptr = (int*)alloc((size_t)(N + 1) * 4);
  int* cursor = (int*)alloc((size_t)N * 4);
  int* slist = (int*)alloc((size_t)ET * 4);
  unsigned int* gib = hbf;  // alias: hbf dead after k_agg; gi = R*48 uints
  (void)ws_size; (void)n_in; (void)out_size;

  hipMemsetAsync(deg, 0, (size_t)N * 4, stream);

  k_count<<<(ET + 255) / 256, 256, 0, stream>>>(ei + E, deg, E, ET);
  k_scan<<<1, 1024, 0, stream>>>(deg, rowptr, cursor, N);
  k_scatter<<<(ET + 255) / 256, 256, 0, stream>>>(ei, ei + E, cursor, slist,
                                                  E, ET);
  k_prep<<<72, 64, 0, stream>>>(lin_w, att_src, att_dst, vbuf);
  k_av<<<(N + 255) / 256, 256, 0, stream>>>(x, vbuf, a_srcb, a_dstb, N);
  k_lin<<<(N + LIN_CHUNK - 1) / LIN_CHUNK, 576, 0, stream>>>(x, lin_w, hbf, N);
  k_agg<<<N, 256, 0, stream>>>(hbf, a_srcb, a_dstb, slist, rowptr, gat_bias,
                               gatbf, N);
  k_gi<<<(R + 63) / 64, 128, 0, stream>>>(gatbf, w_ih, b_ih, gib, R);
  k_rec<<<(N + 7) / 8, 256, 0, stream>>>((const unsigned short*)gib, w_hh,
                                         b_hh, p1w, p1b, p2w, p2b,
                                         (float*)d_out, N);
}

// Round 5
// 179.105 us; speedup vs baseline: 1.9094x; 1.0401x over previous
//
#include <hip/hip_runtime.h>
#include <math.h>

#define HEADS 3
#define C_OUT 384
#define GAT_IN 24
#define HID 32
#define TSTEPS 12
#define NEG_SLOPE 0.2f
#define CAPW 64        // per-wave cached edges in k_aggx
#define GAT_CHUNK 25

__device__ __forceinline__ float sigm(float x) {
  return 1.f / (1.f + __expf(-x));
}
__device__ __forceinline__ float tanh_fast(float x) {
  return 2.f / (1.f + __expf(-2.f * x)) - 1.f;
}
__device__ __forceinline__ unsigned short f2bf(float x) {
  unsigned int u = __float_as_uint(x);
  unsigned int r = u + 0x7fffu + ((u >> 16) & 1u);
  return (unsigned short)(r >> 16);
}
__device__ __forceinline__ unsigned int packbf(float lo, float hi) {
  return (unsigned int)f2bf(lo) | ((unsigned int)f2bf(hi) << 16);
}
__device__ __forceinline__ float bf_lo(unsigned int u) {
  return __uint_as_float(u << 16);
}
__device__ __forceinline__ float bf_hi(unsigned int u) {
  return __uint_as_float(u & 0xffff0000u);
}
__device__ __forceinline__ float bf2f(unsigned short u) {
  return __uint_as_float((unsigned int)u << 16);
}
__device__ __forceinline__ float lrelu(float x) {
  return x >= 0.f ? x : NEG_SLOPE * x;
}

// ---------------- K2a: v_src/v_dst[3][24] = att @ W (fold) -----------------
__global__ __launch_bounds__(64) void k_prep(const float* __restrict__ lin_w,
                                             const float* __restrict__ att_src,
                                             const float* __restrict__ att_dst,
                                             float* __restrict__ vbuf) {
  int b = blockIdx.x;  // 0..71
  int h = b / 24, j = b % 24;
  int lane = threadIdx.x;
  float as = 0.f, ad = 0.f;
  for (int c = lane; c < C_OUT; c += 64) {
    float wv = lin_w[(size_t)(h * C_OUT + c) * GAT_IN + j];
    as += att_src[h * C_OUT + c] * wv;
    ad += att_dst[h * C_OUT + c] * wv;
  }
#pragma unroll
  for (int off = 32; off >= 1; off >>= 1) {
    as += __shfl_xor(as, off, 64);
    ad += __shfl_xor(ad, off, 64);
  }
  if (lane == 0) {
    vbuf[h * 24 + j] = as;
    vbuf[72 + h * 24 + j] = ad;
  }
}

// ---------------- K2b: a_src/a_dst = xf @ v.T (+ zero deg) -----------------
__global__ __launch_bounds__(256) void k_av(const float* __restrict__ xf,
                                            const float* __restrict__ vbuf,
                                            float* __restrict__ a_src,
                                            float* __restrict__ a_dst,
                                            int* __restrict__ deg, int N) {
  __shared__ float s_v[144];
  int tid = threadIdx.x;
  if (tid < 144) s_v[tid] = vbuf[tid];
  __syncthreads();
  int n = blockIdx.x * 256 + tid;
  if (n >= N) return;
  deg[n] = 0;
  float xv[24];
  const float4* xr = (const float4*)(xf + (size_t)n * GAT_IN);
#pragma unroll
  for (int q = 0; q < 6; ++q) {
    float4 t = xr[q];
    xv[4 * q] = t.x; xv[4 * q + 1] = t.y; xv[4 * q + 2] = t.z; xv[4 * q + 3] = t.w;
  }
#pragma unroll
  for (int h = 0; h < 3; ++h) {
    float as = 0.f, ad = 0.f;
#pragma unroll
    for (int j = 0; j < 24; ++j) {
      as += xv[j] * s_v[h * 24 + j];
      ad += xv[j] * s_v[72 + h * 24 + j];
    }
    a_src[n * 3 + h] = as;
    a_dst[n * 3 + h] = ad;
  }
}

// ---------------- CSR build ------------------------------------------------
__global__ void k_count(const int* __restrict__ edst, int* __restrict__ deg,
                        int E, int ET) {
  int e = blockIdx.x * blockDim.x + threadIdx.x;
  if (e >= ET) return;
  int d = (e < E) ? edst[e] : (e - E);
  atomicAdd(&deg[d], 1);
}

__global__ __launch_bounds__(1024) void k_scan(const int* __restrict__ deg,
                                               int* __restrict__ rowptr,
                                               int* __restrict__ cursor,
                                               int n) {
  __shared__ int s_wt[16];
  int tid = threadIdx.x, lane = tid & 63, w = tid >> 6;
  int carry = 0;
  for (int base = 0; base < n; base += 4096) {
    int idx = base + tid * 4;
    int v0 = (idx + 0 < n) ? deg[idx + 0] : 0;
    int v1 = (idx + 1 < n) ? deg[idx + 1] : 0;
    int v2 = (idx + 2 < n) ? deg[idx + 2] : 0;
    int v3 = (idx + 3 < n) ? deg[idx + 3] : 0;
    int s1 = v0 + v1, s2 = s1 + v2, s3 = s2 + v3;
    int v = s3;
#pragma unroll
    for (int off = 1; off < 64; off <<= 1) {
      int t = __shfl_up(v, off, 64);
      if (lane >= off) v += t;
    }
    if (lane == 63) s_wt[w] = v;
    __syncthreads();
    if (w == 0) {
      int x = (lane < 16) ? s_wt[lane] : 0;
#pragma unroll
      for (int off = 1; off < 16; off <<= 1) {
        int t = __shfl_up(x, off, 64);
        if (lane >= off) x += t;
      }
      if (lane < 16) s_wt[lane] = x;
    }
    __syncthreads();
    int wexcl = (w == 0) ? 0 : s_wt[w - 1];
    int total = s_wt[15];
    int excl = carry + wexcl + v - s3;
    if (idx + 0 < n) { rowptr[idx + 0] = excl;      cursor[idx + 0] = excl; }
    if (idx + 1 < n) { rowptr[idx + 1] = excl + v0; cursor[idx + 1] = excl + v0; }
    if (idx + 2 < n) { rowptr[idx + 2] = excl + s1; cursor[idx + 2] = excl + s1; }
    if (idx + 3 < n) { rowptr[idx + 3] = excl + s2; cursor[idx + 3] = excl + s2; }
    carry += total;
    __syncthreads();
  }
  if (tid == 0) rowptr[n] = carry;
}

__global__ void k_scatter(const int* __restrict__ esrc,
                          const int* __restrict__ edst,
                          int* __restrict__ cursor, int* __restrict__ slist,
                          int E, int ET) {
  int e = blockIdx.x * blockDim.x + threadIdx.x;
  if (e >= ET) return;
  int d, s;
  if (e < E) { d = edst[e]; s = esrc[e]; }
  else { d = e - E; s = e - E; }
  int pos = atomicAdd(&cursor[d], 1);
  slist[pos] = s;
}

// ---------------- K6: softmax + xf-space aggregation (L2-resident) ---------
// Y[n, h*24+c] = sum_e softmax_w[e,h] * xf[src(e), c]
// 256 threads = 4 waves; one dst node per wave.
__global__ __launch_bounds__(256) void k_aggx(
    const float* __restrict__ xf, const float* __restrict__ a_src,
    const float* __restrict__ a_dst, const int* __restrict__ slist,
    const int* __restrict__ rowptr, float* __restrict__ Y, int N) {
  __shared__ int s_src[4][CAPW];
  __shared__ float s_w[4][CAPW][3];
  int tid = threadIdx.x, lane = tid & 63, wv = tid >> 6;
  int n = blockIdx.x * 4 + wv;
  if (n >= N) return;  // per-wave exit; no barriers used
  int start = rowptr[n], deg = rowptr[n + 1] - start;
  float ad0 = a_dst[n * 3 + 0], ad1 = a_dst[n * 3 + 1], ad2 = a_dst[n * 3 + 2];

  // pass A: exp(alpha) + wave-sum (logits bounded => no max-shift needed)
  float t0 = 0.f, t1 = 0.f, t2 = 0.f;
  for (int i = lane; i < deg; i += 64) {
    int s = slist[start + i];
    float e0 = __expf(lrelu(a_src[s * 3 + 0] + ad0));
    float e1 = __expf(lrelu(a_src[s * 3 + 1] + ad1));
    float e2 = __expf(lrelu(a_src[s * 3 + 2] + ad2));
    if (i < CAPW) {
      s_src[wv][i] = s;
      s_w[wv][i][0] = e0; s_w[wv][i][1] = e1; s_w[wv][i][2] = e2;
    }
    t0 += e0; t1 += e1; t2 += e2;
  }
#pragma unroll
  for (int off = 32; off >= 1; off >>= 1) {
    t0 += __shfl_xor(t0, off, 64);
    t1 += __shfl_xor(t1, off, 64);
    t2 += __shfl_xor(t2, off, 64);
  }
  float inv0 = 1.f / t0, inv1 = 1.f / t1, inv2 = 1.f / t2;

  // pass B: 2 edge-slots x 24 active channel-lanes; xf gather is L2-resident
  int eg = lane >> 5;   // edge slot 0/1
  int c = lane & 31;    // channel (active c<24)
  float acc0 = 0.f, acc1 = 0.f, acc2 = 0.f;
  if (deg <= CAPW) {
#pragma unroll 2
    for (int i = eg; i < deg; i += 2) {
      int s = s_src[wv][i];
      float w0 = s_w[wv][i][0] * inv0;
      float w1 = s_w[wv][i][1] * inv1;
      float w2 = s_w[wv][i][2] * inv2;
      float xv = (c < 24) ? xf[(size_t)s * 24 + c] : 0.f;
      acc0 += w0 * xv; acc1 += w1 * xv; acc2 += w2 * xv;
    }
  } else {
    for (int i = eg; i < deg; i += 2) {
      int s = slist[start + i];
      float w0 = __expf(lrelu(a_src[s * 3 + 0] + ad0)) * inv0;
      float w1 = __expf(lrelu(a_src[s * 3 + 1] + ad1)) * inv1;
      float w2 = __expf(lrelu(a_src[s * 3 + 2] + ad2)) * inv2;
      float xv = (c < 24) ? xf[(size_t)s * 24 + c] : 0.f;
      acc0 += w0 * xv; acc1 += w1 * xv; acc2 += w2 * xv;
    }
  }
  acc0 += __shfl_xor(acc0, 32, 64);
  acc1 += __shfl_xor(acc1, 32, 64);
  acc2 += __shfl_xor(acc2, 32, 64);
  if (lane < 24) {
    float* yr = Y + (size_t)n * 72;
    yr[lane] = acc0;
    yr[24 + lane] = acc1;
    yr[48 + lane] = acc2;
  }
}

// ---------------- K6b: gat(bf16) = mean_h(Y_h @ lin_w_h^T) + bias ----------
// Thread owns output channel c; 72 weights in registers; Y reads are
// block-uniform -> scalar loads.
__global__ __launch_bounds__(384) void k_gat(const float* __restrict__ Y,
                                             const float* __restrict__ lin_w,
                                             const float* __restrict__ gat_bias,
                                             unsigned short* __restrict__ gatbf,
                                             int N) {
  int c = threadIdx.x;  // 0..383
  float w0[24], w1[24], w2[24];
  {
    const float4* p0 = (const float4*)(lin_w + (size_t)c * GAT_IN);
    const float4* p1 = (const float4*)(lin_w + (size_t)(C_OUT + c) * GAT_IN);
    const float4* p2 = (const float4*)(lin_w + (size_t)(2 * C_OUT + c) * GAT_IN);
#pragma unroll
    for (int q = 0; q < 6; ++q) {
      float4 a = p0[q], b = p1[q], d = p2[q];
      w0[4 * q] = a.x; w0[4 * q + 1] = a.y; w0[4 * q + 2] = a.z; w0[4 * q + 3] = a.w;
      w1[4 * q] = b.x; w1[4 * q + 1] = b.y; w1[4 * q + 2] = b.z; w1[4 * q + 3] = b.w;
      w2[4 * q] = d.x; w2[4 * q + 1] = d.y; w2[4 * q + 2] = d.z; w2[4 * q + 3] = d.w;
    }
  }
  float bias = gat_bias[c];
  int n0 = blockIdx.x * GAT_CHUNK;
  int n1 = min(n0 + GAT_CHUNK, N);
  for (int n = n0; n < n1; ++n) {
    const float* yr = Y + (size_t)n * 72;
    float a0 = 0.f, a1 = 0.f, a2 = 0.f;
#pragma unroll
    for (int j = 0; j < 24; ++j) {
      a0 += yr[j] * w0[j];
      a1 += yr[24 + j] * w1[j];
      a2 += yr[48 + j] * w2[j];
    }
    gatbf[(size_t)n * C_OUT + c] = f2bf((a0 + a1 + a2) * (1.f / 3.f) + bias);
  }
}

// ---------------- K7a: gi(bf16) = gat(bf16) @ w_ih.T + b_ih ----------------
__global__ __launch_bounds__(128) void k_gi(const unsigned int* __restrict__ A,
                                            const float* __restrict__ wih,
                                            const float* __restrict__ bih,
                                            unsigned int* __restrict__ gi,
                                            int R) {
  __shared__ float At[32][68];
  __shared__ float Bt[32][100];
  __shared__ float s_bias[96];
  int tid = threadIdx.x;
  int row0 = blockIdx.x * 64;
  {
    int r = tid >> 1;    // local row 0..63
    int half = tid & 1;  // which 16-k half
    int row = row0 + r;
    int rc = min(row, R - 1);
    const unsigned int* ar = A + (size_t)rc * 16 + half * 8;
    uint4 a0 = *(const uint4*)ar;
    uint4 a1 = *(const uint4*)(ar + 4);
    int k0 = half * 16;
    At[k0 + 0][r] = bf_lo(a0.x);  At[k0 + 1][r] = bf_hi(a0.x);
    At[k0 + 2][r] = bf_lo(a0.y);  At[k0 + 3][r] = bf_hi(a0.y);
    At[k0 + 4][r] = bf_lo(a0.z);  At[k0 + 5][r] = bf_hi(a0.z);
    At[k0 + 6][r] = bf_lo(a0.w);  At[k0 + 7][r] = bf_hi(a0.w);
    At[k0 + 8][r] = bf_lo(a1.x);  At[k0 + 9][r] = bf_hi(a1.x);
    At[k0 + 10][r] = bf_lo(a1.y); At[k0 + 11][r] = bf_hi(a1.y);
    At[k0 + 12][r] = bf_lo(a1.z); At[k0 + 13][r] = bf_hi(a1.z);
    At[k0 + 14][r] = bf_lo(a1.w); At[k0 + 15][r] = bf_hi(a1.w);
  }
#pragma unroll
  for (int q = 0; q < 6; ++q) {
    int fid = q * 128 + tid;
    int c = fid >> 3;
    int k4 = (fid & 7) * 4;
    float4 b = *(const float4*)(wih + (size_t)c * 32 + k4);
    Bt[k4 + 0][c] = b.x;
    Bt[k4 + 1][c] = b.y;
    Bt[k4 + 2][c] = b.z;
    Bt[k4 + 3][c] = b.w;
  }
  if (tid < 96) s_bias[tid] = bih[tid];
  __syncthreads();
  int rowg = tid & 7;
  int colg = tid >> 3;
  int r0 = rowg * 8, c0 = colg * 6;
  float acc[8][6];
#pragma unroll
  for (int i = 0; i < 8; ++i)
#pragma unroll
    for (int j = 0; j < 6; ++j) acc[i][j] = 0.f;
#pragma unroll 4
  for (int k = 0; k < 32; ++k) {
    float4 a0 = *(const float4*)&At[k][r0];
    float4 a1 = *(const float4*)&At[k][r0 + 4];
    float b[6];
#pragma unroll
    for (int j = 0; j < 6; ++j) b[j] = Bt[k][c0 + j];
    float av[8] = {a0.x, a0.y, a0.z, a0.w, a1.x, a1.y, a1.z, a1.w};
#pragma unroll
    for (int i = 0; i < 8; ++i)
#pragma unroll
      for (int j = 0; j < 6; ++j) acc[i][j] += av[i] * b[j];
  }
#pragma unroll
  for (int i = 0; i < 8; ++i) {
    int row = row0 + r0 + i;
    if (row < R) {
      unsigned int* crow = gi + (size_t)row * 48 + (c0 >> 1);
#pragma unroll
      for (int jj = 0; jj < 3; ++jj) {
        float lo = acc[i][2 * jj] + s_bias[c0 + 2 * jj];
        float hi = acc[i][2 * jj + 1] + s_bias[c0 + 2 * jj + 1];
        crow[jj] = packbf(lo, hi);
      }
    }
  }
}

// ---------------- K7b: GRU recurrence + projections ------------------------
__global__ __launch_bounds__(256) void k_rec(
    const unsigned short* __restrict__ gi, const float* __restrict__ whh,
    const float* __restrict__ bhh, const float* __restrict__ p1w,
    const float* __restrict__ p1b, const float* __restrict__ p2w,
    const float* __restrict__ p2b, float* __restrict__ out, int N) {
  __shared__ float h_hist[8][13][36];
  __shared__ float s_o[8][12];
  int tid = threadIdx.x;
  int nd = tid >> 5;
  int k = tid & 31;
  int node = blockIdx.x * 8 + nd;
  if (node >= N) return;  // no barriers below -> safe

  float wr[32], wz[32], wn[32];
  {
    const float4* pr = (const float4*)(whh + (size_t)k * HID);
    const float4* pz = (const float4*)(whh + (size_t)(HID + k) * HID);
    const float4* pn = (const float4*)(whh + (size_t)(2 * HID + k) * HID);
#pragma unroll
    for (int j = 0; j < 8; ++j) {
      float4 a = pr[j], b = pz[j], c = pn[j];
      wr[4 * j] = a.x; wr[4 * j + 1] = a.y; wr[4 * j + 2] = a.z; wr[4 * j + 3] = a.w;
      wz[4 * j] = b.x; wz[4 * j + 1] = b.y; wz[4 * j + 2] = b.z; wz[4 * j + 3] = b.w;
      wn[4 * j] = c.x; wn[4 * j + 1] = c.y; wn[4 * j + 2] = c.z; wn[4 * j + 3] = c.w;
    }
  }
  float bhr = bhh[k], bhz = bhh[HID + k], bhn = bhh[2 * HID + k];
  h_hist[nd][0][k] = 0.f;
  float h = 0.f;
  const unsigned short* girow = gi + (size_t)node * TSTEPS * 96;
  for (int t = 0; t < TSTEPS; ++t) {
    float gr = bf2f(girow[t * 96 + k]);
    float gz = bf2f(girow[t * 96 + 32 + k]);
    float gn = bf2f(girow[t * 96 + 64 + k]);
    float ar = 0.f, az = 0.f, an = 0.f;
    const float* hh = &h_hist[nd][t][0];
#pragma unroll
    for (int q = 0; q < 8; ++q) {
      float4 hp = *(const float4*)(hh + q * 4);
      ar += wr[4 * q] * hp.x + wr[4 * q + 1] * hp.y + wr[4 * q + 2] * hp.z +
            wr[4 * q + 3] * hp.w;
      az += wz[4 * q] * hp.x + wz[4 * q + 1] * hp.y + wz[4 * q + 2] * hp.z +
            wz[4 * q + 3] * hp.w;
      an += wn[4 * q] * hp.x + wn[4 * q + 1] * hp.y + wn[4 * q + 2] * hp.z +
            wn[4 * q + 3] * hp.w;
    }
    float r = sigm(gr + ar + bhr);
    float z = sigm(gz + az + bhz);
    float nn = tanh_fast(gn + r * (an + bhn));
    float hnew = (1.f - z) * nn + z * h;
    h = hnew;
    h_hist[nd][t + 1][k] = hnew;
  }
  if (k < TSTEPS) {
    float o = p1b[0];
#pragma unroll
    for (int kk = 0; kk < HID; ++kk) o += h_hist[nd][k + 1][kk] * p1w[kk];
    s_o[nd][k] = o;
  }
  if (k < TSTEPS) {
    float acc = p2b[k];
#pragma unroll
    for (int s2 = 0; s2 < TSTEPS; ++s2)
      acc += p2w[k * TSTEPS + s2] * s_o[nd][s2];
    out[(size_t)node * TSTEPS + k] = acc;
  }
}

// ---------------------------------------------------------------------------
extern "C" void kernel_launch(void* const* d_in, const int* in_sizes, int n_in,
                              void* d_out, int out_size, void* d_ws,
                              size_t ws_size, hipStream_t stream) {
  const float* x = (const float*)d_in[0];
  const int* ei = (const int*)d_in[1];
  const float* lin_w = (const float*)d_in[2];
  const float* att_src = (const float*)d_in[3];
  const float* att_dst = (const float*)d_in[4];
  const float* gat_bias = (const float*)d_in[5];
  const float* w_ih = (const float*)d_in[6];
  const float* w_hh = (const float*)d_in[7];
  const float* b_ih = (const float*)d_in[8];
  const float* b_hh = (const float*)d_in[9];
  const float* p1w = (const float*)d_in[10];
  const float* p1b = (const float*)d_in[11];
  const float* p2w = (const float*)d_in[12];
  const float* p2b = (const float*)d_in[13];

  int N = in_sizes[0] / GAT_IN;  // 10000
  int E = in_sizes[1] / 2;       // 160000
  int ET = E + N;
  int R = N * TSTEPS;            // 120000

  size_t off = 0;
  char* base = (char*)d_ws;
  auto alloc = [&](size_t bytes) {
    void* p = base + off;
    off += (bytes + 255) & ~(size_t)255;
    return p;
  };
  unsigned int* gib = (unsigned int*)alloc((size_t)R * 48 * 4);       // bf16 gi
  unsigned short* gatbf = (unsigned short*)alloc((size_t)N * C_OUT * 2);
  float* Yb = (float*)alloc((size_t)N * 72 * 4);
  float* a_srcb = (float*)alloc((size_t)N * 3 * 4);
  float* a_dstb = (float*)alloc((size_t)N * 3 * 4);
  float* vbuf = (float*)alloc(144 * 4);
  int* deg = (int*)alloc((size_t)N * 4);
  int* rowptr = (int*)alloc((size_t)(N + 1) * 4);
  int* cursor = (int*)alloc((size_t)N * 4);
  int* slist = (int*)alloc((size_t)ET * 4);
  (void)ws_size; (void)n_in; (void)out_size;

  k_prep<<<72, 64, 0, stream>>>(lin_w, att_src, att_dst, vbuf);
  k_av<<<(N + 255) / 256, 256, 0, stream>>>(x, vbuf, a_srcb, a_dstb, deg, N);
  k_count<<<(ET + 255) / 256, 256, 0, stream>>>(ei + E, deg, E, ET);
  k_scan<<<1, 1024, 0, stream>>>(deg, rowptr, cursor, N);
  k_scatter<<<(ET + 255) / 256, 256, 0, stream>>>(ei, ei + E, cursor, slist,
                                                  E, ET);
  k_aggx<<<(N + 3) / 4, 256, 0, stream>>>(x, a_srcb, a_dstb, slist, rowptr,
                                          Yb, N);
  k_gat<<<(N + GAT_CHUNK - 1) / GAT_CHUNK, 384, 0, stream>>>(Yb, lin_w,
                                                             gat_bias, gatbf,
                                                             N);
  k_gi<<<(R + 63) / 64, 128, 0, stream>>>((const unsigned int*)gatbf, w_ih,
                                          b_ih, gib, R);
  k_rec<<<(N + 7) / 8, 256, 0, stream>>>((const unsigned short*)gib, w_hh,
                                         b_hh, p1w, p1b, p2w, p2b,
                                         (float*)d_out, N);
}

// Round 6
// 146.648 us; speedup vs baseline: 2.3320x; 1.2213x over previous
//
#include <hip/hip_runtime.h>
#include <math.h>

#define HEADS 3
#define C_OUT 384
#define GAT_IN 24
#define HID 32
#define TSTEPS 12
#define NEG_SLOPE 0.2f
#define CAPW 64        // per-wave cached edges in k_aggx

__device__ __forceinline__ float sigm(float x) {
  return 1.f / (1.f + __expf(-x));
}
__device__ __forceinline__ float tanh_fast(float x) {
  return 2.f / (1.f + __expf(-2.f * x)) - 1.f;
}
__device__ __forceinline__ unsigned short f2bf(float x) {
  unsigned int u = __float_as_uint(x);
  unsigned int r = u + 0x7fffu + ((u >> 16) & 1u);
  return (unsigned short)(r >> 16);
}
__device__ __forceinline__ unsigned int packbf(float lo, float hi) {
  return (unsigned int)f2bf(lo) | ((unsigned int)f2bf(hi) << 16);
}
__device__ __forceinline__ float bf2f(unsigned short u) {
  return __uint_as_float((unsigned int)u << 16);
}
__device__ __forceinline__ float lrelu(float x) {
  return x >= 0.f ? x : NEG_SLOPE * x;
}

// ---------------- K2a: v_src/v_dst[3][24] = att @ W (fold) -----------------
__global__ __launch_bounds__(64) void k_prep(const float* __restrict__ lin_w,
                                             const float* __restrict__ att_src,
                                             const float* __restrict__ att_dst,
                                             float* __restrict__ vbuf) {
  int b = blockIdx.x;  // 0..71
  int h = b / 24, j = b % 24;
  int lane = threadIdx.x;
  float as = 0.f, ad = 0.f;
  for (int c = lane; c < C_OUT; c += 64) {
    float wv = lin_w[(size_t)(h * C_OUT + c) * GAT_IN + j];
    as += att_src[h * C_OUT + c] * wv;
    ad += att_dst[h * C_OUT + c] * wv;
  }
#pragma unroll
  for (int off = 32; off >= 1; off >>= 1) {
    as += __shfl_xor(as, off, 64);
    ad += __shfl_xor(ad, off, 64);
  }
  if (lane == 0) {
    vbuf[h * 24 + j] = as;
    vbuf[72 + h * 24 + j] = ad;
  }
}

// ---------------- K_fold: WW[t][k][g] (k<72) and bb row (k==72) ------------
// WW[t][k=h*24+j][g] = sum_c' lin_w[(h*384 + t*32 + c')*24 + j]/3 * wih[g][c']
// WW[t][72][g]       = sum_c' gat_bias[t*32+c'] * wih[g][c'] + bih[g]
__global__ __launch_bounds__(96) void k_fold(const float* __restrict__ lin_w,
                                             const float* __restrict__ gat_bias,
                                             const float* __restrict__ wih,
                                             const float* __restrict__ bih,
                                             float* __restrict__ WW) {
  int t = blockIdx.x;  // 0..11
  int k = blockIdx.y;  // 0..72
  int g = threadIdx.x; // 0..95
  __shared__ float s_w[32];
  if (g < 32) {
    if (k < 72) {
      int h = k / 24, j = k % 24;
      s_w[g] = lin_w[(size_t)(h * C_OUT + t * 32 + g) * GAT_IN + j] * (1.f / 3.f);
    } else {
      s_w[g] = gat_bias[t * 32 + g];
    }
  }
  __syncthreads();
  const float* wrow = wih + (size_t)g * 32;
  float acc = 0.f;
#pragma unroll
  for (int c = 0; c < 32; ++c) acc += s_w[c] * wrow[c];
  if (k == 72) acc += bih[g];
  WW[((size_t)t * 73 + k) * 96 + g] = acc;
}

// ---------------- K2b: a_src/a_dst = xf @ v.T (+ zero deg) -----------------
__global__ __launch_bounds__(256) void k_av(const float* __restrict__ xf,
                                            const float* __restrict__ vbuf,
                                            float* __restrict__ a_src,
                                            float* __restrict__ a_dst,
                                            int* __restrict__ deg, int N) {
  __shared__ float s_v[144];
  int tid = threadIdx.x;
  if (tid < 144) s_v[tid] = vbuf[tid];
  __syncthreads();
  int n = blockIdx.x * 256 + tid;
  if (n >= N) return;
  deg[n] = 0;
  float xv[24];
  const float4* xr = (const float4*)(xf + (size_t)n * GAT_IN);
#pragma unroll
  for (int q = 0; q < 6; ++q) {
    float4 t = xr[q];
    xv[4 * q] = t.x; xv[4 * q + 1] = t.y; xv[4 * q + 2] = t.z; xv[4 * q + 3] = t.w;
  }
#pragma unroll
  for (int h = 0; h < 3; ++h) {
    float as = 0.f, ad = 0.f;
#pragma unroll
    for (int j = 0; j < 24; ++j) {
      as += xv[j] * s_v[h * 24 + j];
      ad += xv[j] * s_v[72 + h * 24 + j];
    }
    a_src[n * 3 + h] = as;
    a_dst[n * 3 + h] = ad;
  }
}

// ---------------- CSR build ------------------------------------------------
__global__ void k_count(const int* __restrict__ edst, int* __restrict__ deg,
                        int E, int ET) {
  int e = blockIdx.x * blockDim.x + threadIdx.x;
  if (e >= ET) return;
  int d = (e < E) ? edst[e] : (e - E);
  atomicAdd(&deg[d], 1);
}

__global__ __launch_bounds__(1024) void k_scan(const int* __restrict__ deg,
                                               int* __restrict__ rowptr,
                                               int* __restrict__ cursor,
                                               int n) {
  __shared__ int s_wt[16];
  int tid = threadIdx.x, lane = tid & 63, w = tid >> 6;
  int carry = 0;
  for (int base = 0; base < n; base += 4096) {
    int idx = base + tid * 4;
    int v0 = (idx + 0 < n) ? deg[idx + 0] : 0;
    int v1 = (idx + 1 < n) ? deg[idx + 1] : 0;
    int v2 = (idx + 2 < n) ? deg[idx + 2] : 0;
    int v3 = (idx + 3 < n) ? deg[idx + 3] : 0;
    int s1 = v0 + v1, s2 = s1 + v2, s3 = s2 + v3;
    int v = s3;
#pragma unroll
    for (int off = 1; off < 64; off <<= 1) {
      int t = __shfl_up(v, off, 64);
      if (lane >= off) v += t;
    }
    if (lane == 63) s_wt[w] = v;
    __syncthreads();
    if (w == 0) {
      int x = (lane < 16) ? s_wt[lane] : 0;
#pragma unroll
      for (int off = 1; off < 16; off <<= 1) {
        int t = __shfl_up(x, off, 64);
        if (lane >= off) x += t;
      }
      if (lane < 16) s_wt[lane] = x;
    }
    __syncthreads();
    int wexcl = (w == 0) ? 0 : s_wt[w - 1];
    int total = s_wt[15];
    int excl = carry + wexcl + v - s3;
    if (idx + 0 < n) { rowptr[idx + 0] = excl;      cursor[idx + 0] = excl; }
    if (idx + 1 < n) { rowptr[idx + 1] = excl + v0; cursor[idx + 1] = excl + v0; }
    if (idx + 2 < n) { rowptr[idx + 2] = excl + s1; cursor[idx + 2] = excl + s1; }
    if (idx + 3 < n) { rowptr[idx + 3] = excl + s2; cursor[idx + 3] = excl + s2; }
    carry += total;
    __syncthreads();
  }
  if (tid == 0) rowptr[n] = carry;
}

__global__ void k_scatter(const int* __restrict__ esrc,
                          const int* __restrict__ edst,
                          int* __restrict__ cursor, int* __restrict__ slist,
                          int E, int ET) {
  int e = blockIdx.x * blockDim.x + threadIdx.x;
  if (e >= ET) return;
  int d, s;
  if (e < E) { d = edst[e]; s = esrc[e]; }
  else { d = e - E; s = e - E; }
  int pos = atomicAdd(&cursor[d], 1);
  slist[pos] = s;
}

// ---------------- K6: softmax + xf-space aggregation (L2-resident) ---------
__global__ __launch_bounds__(256) void k_aggx(
    const float* __restrict__ xf, const float* __restrict__ a_src,
    const float* __restrict__ a_dst, const int* __restrict__ slist,
    const int* __restrict__ rowptr, float* __restrict__ Y, int N) {
  __shared__ int s_src[4][CAPW];
  __shared__ float s_w[4][CAPW][3];
  int tid = threadIdx.x, lane = tid & 63, wv = tid >> 6;
  int n = blockIdx.x * 4 + wv;
  if (n >= N) return;  // per-wave exit; no barriers used
  int start = rowptr[n], deg = rowptr[n + 1] - start;
  float ad0 = a_dst[n * 3 + 0], ad1 = a_dst[n * 3 + 1], ad2 = a_dst[n * 3 + 2];

  // pass A: exp(alpha) + wave-sum (logits bounded => no max-shift needed)
  float t0 = 0.f, t1 = 0.f, t2 = 0.f;
  for (int i = lane; i < deg; i += 64) {
    int s = slist[start + i];
    float e0 = __expf(lrelu(a_src[s * 3 + 0] + ad0));
    float e1 = __expf(lrelu(a_src[s * 3 + 1] + ad1));
    float e2 = __expf(lrelu(a_src[s * 3 + 2] + ad2));
    if (i < CAPW) {
      s_src[wv][i] = s;
      s_w[wv][i][0] = e0; s_w[wv][i][1] = e1; s_w[wv][i][2] = e2;
    }
    t0 += e0; t1 += e1; t2 += e2;
  }
#pragma unroll
  for (int off = 32; off >= 1; off >>= 1) {
    t0 += __shfl_xor(t0, off, 64);
    t1 += __shfl_xor(t1, off, 64);
    t2 += __shfl_xor(t2, off, 64);
  }
  float inv0 = 1.f / t0, inv1 = 1.f / t1, inv2 = 1.f / t2;

  // pass B: 2 edge-slots x 24 active channel-lanes; xf gather is L2-resident
  int eg = lane >> 5;   // edge slot 0/1
  int c = lane & 31;    // channel (active c<24)
  float acc0 = 0.f, acc1 = 0.f, acc2 = 0.f;
  if (deg <= CAPW) {
#pragma unroll 2
    for (int i = eg; i < deg; i += 2) {
      int s = s_src[wv][i];
      float w0 = s_w[wv][i][0] * inv0;
      float w1 = s_w[wv][i][1] * inv1;
      float w2 = s_w[wv][i][2] * inv2;
      float xv = (c < 24) ? xf[(size_t)s * 24 + c] : 0.f;
      acc0 += w0 * xv; acc1 += w1 * xv; acc2 += w2 * xv;
    }
  } else {
    for (int i = eg; i < deg; i += 2) {
      int s = slist[start + i];
      float w0 = __expf(lrelu(a_src[s * 3 + 0] + ad0)) * inv0;
      float w1 = __expf(lrelu(a_src[s * 3 + 1] + ad1)) * inv1;
      float w2 = __expf(lrelu(a_src[s * 3 + 2] + ad2)) * inv2;
      float xv = (c < 24) ? xf[(size_t)s * 24 + c] : 0.f;
      acc0 += w0 * xv; acc1 += w1 * xv; acc2 += w2 * xv;
    }
  }
  acc0 += __shfl_xor(acc0, 32, 64);
  acc1 += __shfl_xor(acc1, 32, 64);
  acc2 += __shfl_xor(acc2, 32, 64);
  if (lane < 24) {
    float* yr = Y + (size_t)n * 72;
    yr[lane] = acc0;
    yr[24 + lane] = acc1;
    yr[48 + lane] = acc2;
  }
}

// ---------------- K_gi2: gi(bf16) = Y @ WW[t] + bb[t] ----------------------
// M=N rows, per block: 64 rows x 96 cols (t = blockIdx.y), K=72.
__global__ __launch_bounds__(128) void k_gi2(const float* __restrict__ Y,
                                             const float* __restrict__ WW,
                                             unsigned int* __restrict__ gi,
                                             int N) {
  __shared__ float At[72][68];
  __shared__ float Bt[72][100];
  __shared__ float s_bias[96];
  int tid = threadIdx.x;
  int row0 = blockIdx.x * 64;
  int t = blockIdx.y;
  const float* WWt = WW + (size_t)t * 73 * 96;
  {
    int r = tid >> 1, half = tid & 1;
    int rc = min(row0 + r, N - 1);
    const float4* yr = (const float4*)(Y + (size_t)rc * 72 + half * 36);
#pragma unroll
    for (int q = 0; q < 9; ++q) {
      float4 a = yr[q];
      int kk = half * 36 + q * 4;
      At[kk + 0][r] = a.x; At[kk + 1][r] = a.y;
      At[kk + 2][r] = a.z; At[kk + 3][r] = a.w;
    }
  }
  for (int fid = tid; fid < 1728; fid += 128) {
    int k = fid / 24, gq = (fid % 24) * 4;
    float4 b = *(const float4*)(WWt + (size_t)k * 96 + gq);
    Bt[k][gq + 0] = b.x; Bt[k][gq + 1] = b.y;
    Bt[k][gq + 2] = b.z; Bt[k][gq + 3] = b.w;
  }
  if (tid < 96) s_bias[tid] = WWt[72 * 96 + tid];
  __syncthreads();
  int r0 = (tid & 7) * 8, c0 = (tid >> 3) * 6;
  float acc[8][6];
#pragma unroll
  for (int i = 0; i < 8; ++i)
#pragma unroll
    for (int j = 0; j < 6; ++j) acc[i][j] = 0.f;
#pragma unroll 4
  for (int k = 0; k < 72; ++k) {
    float4 a0 = *(const float4*)&At[k][r0];
    float4 a1 = *(const float4*)&At[k][r0 + 4];
    float b[6];
#pragma unroll
    for (int j = 0; j < 6; ++j) b[j] = Bt[k][c0 + j];
    float av[8] = {a0.x, a0.y, a0.z, a0.w, a1.x, a1.y, a1.z, a1.w};
#pragma unroll
    for (int i = 0; i < 8; ++i)
#pragma unroll
      for (int j = 0; j < 6; ++j) acc[i][j] += av[i] * b[j];
  }
#pragma unroll
  for (int i = 0; i < 8; ++i) {
    int n = row0 + r0 + i;
    if (n < N) {
      unsigned int* crow = gi + (size_t)n * 576 + (t * 96 + c0) / 2;
#pragma unroll
      for (int jj = 0; jj < 3; ++jj) {
        float lo = acc[i][2 * jj] + s_bias[c0 + 2 * jj];
        float hi = acc[i][2 * jj + 1] + s_bias[c0 + 2 * jj + 1];
        crow[jj] = packbf(lo, hi);
      }
    }
  }
}

// ---------------- K7b: GRU recurrence + projections ------------------------
__global__ __launch_bounds__(256) void k_rec(
    const unsigned short* __restrict__ gi, const float* __restrict__ whh,
    const float* __restrict__ bhh, const float* __restrict__ p1w,
    const float* __restrict__ p1b, const float* __restrict__ p2w,
    const float* __restrict__ p2b, float* __restrict__ out, int N) {
  __shared__ float h_hist[8][13][36];
  __shared__ float s_o[8][12];
  int tid = threadIdx.x;
  int nd = tid >> 5;
  int k = tid & 31;
  int node = blockIdx.x * 8 + nd;
  if (node >= N) return;  // no barriers below -> safe

  float wr[32], wz[32], wn[32];
  {
    const float4* pr = (const float4*)(whh + (size_t)k * HID);
    const float4* pz = (const float4*)(whh + (size_t)(HID + k) * HID);
    const float4* pn = (const float4*)(whh + (size_t)(2 * HID + k) * HID);
#pragma unroll
    for (int j = 0; j < 8; ++j) {
      float4 a = pr[j], b = pz[j], c = pn[j];
      wr[4 * j] = a.x; wr[4 * j + 1] = a.y; wr[4 * j + 2] = a.z; wr[4 * j + 3] = a.w;
      wz[4 * j] = b.x; wz[4 * j + 1] = b.y; wz[4 * j + 2] = b.z; wz[4 * j + 3] = b.w;
      wn[4 * j] = c.x; wn[4 * j + 1] = c.y; wn[4 * j + 2] = c.z; wn[4 * j + 3] = c.w;
    }
  }
  float bhr = bhh[k], bhz = bhh[HID + k], bhn = bhh[2 * HID + k];
  h_hist[nd][0][k] = 0.f;
  float h = 0.f;
  const unsigned short* girow = gi + (size_t)node * TSTEPS * 96;
  for (int t = 0; t < TSTEPS; ++t) {
    float gr = bf2f(girow[t * 96 + k]);
    float gz = bf2f(girow[t * 96 + 32 + k]);
    float gn = bf2f(girow[t * 96 + 64 + k]);
    float ar = 0.f, az = 0.f, an = 0.f;
    const float* hh = &h_hist[nd][t][0];
#pragma unroll
    for (int q = 0; q < 8; ++q) {
      float4 hp = *(const float4*)(hh + q * 4);
      ar += wr[4 * q] * hp.x + wr[4 * q + 1] * hp.y + wr[4 * q + 2] * hp.z +
            wr[4 * q + 3] * hp.w;
      az += wz[4 * q] * hp.x + wz[4 * q + 1] * hp.y + wz[4 * q + 2] * hp.z +
            wz[4 * q + 3] * hp.w;
      an += wn[4 * q] * hp.x + wn[4 * q + 1] * hp.y + wn[4 * q + 2] * hp.z +
            wn[4 * q + 3] * hp.w;
    }
    float r = sigm(gr + ar + bhr);
    float z = sigm(gz + az + bhz);
    float nn = tanh_fast(gn + r * (an + bhn));
    float hnew = (1.f - z) * nn + z * h;
    h = hnew;
    h_hist[nd][t + 1][k] = hnew;
  }
  if (k < TSTEPS) {
    float o = p1b[0];
#pragma unroll
    for (int kk = 0; kk < HID; ++kk) o += h_hist[nd][k + 1][kk] * p1w[kk];
    s_o[nd][k] = o;
  }
  if (k < TSTEPS) {
    float acc = p2b[k];
#pragma unroll
    for (int s2 = 0; s2 < TSTEPS; ++s2)
      acc += p2w[k * TSTEPS + s2] * s_o[nd][s2];
    out[(size_t)node * TSTEPS + k] = acc;
  }
}

// ---------------------------------------------------------------------------
extern "C" void kernel_launch(void* const* d_in, const int* in_sizes, int n_in,
                              void* d_out, int out_size, void* d_ws,
                              size_t ws_size, hipStream_t stream) {
  const float* x = (const float*)d_in[0];
  const int* ei = (const int*)d_in[1];
  const float* lin_w = (const float*)d_in[2];
  const float* att_src = (const float*)d_in[3];
  const float* att_dst = (const float*)d_in[4];
  const float* gat_bias = (const float*)d_in[5];
  const float* w_ih = (const float*)d_in[6];
  const float* w_hh = (const float*)d_in[7];
  const float* b_ih = (const float*)d_in[8];
  const float* b_hh = (const float*)d_in[9];
  const float* p1w = (const float*)d_in[10];
  const float* p1b = (const float*)d_in[11];
  const float* p2w = (const float*)d_in[12];
  const float* p2b = (const float*)d_in[13];

  int N = in_sizes[0] / GAT_IN;  // 10000
  int E = in_sizes[1] / 2;       // 160000
  int ET = E + N;

  size_t off = 0;
  char* base = (char*)d_ws;
  auto alloc = [&](size_t bytes) {
    void* p = base + off;
    off += (bytes + 255) & ~(size_t)255;
    return p;
  };
  unsigned int* gib = (unsigned int*)alloc((size_t)N * 576 * 4);  // bf16 gi
  float* Yb = (float*)alloc((size_t)N * 72 * 4);
  float* WW = (float*)alloc((size_t)12 * 73 * 96 * 4);
  float* a_srcb = (float*)alloc((size_t)N * 3 * 4);
  float* a_dstb = (float*)alloc((size_t)N * 3 * 4);
  float* vbuf = (float*)alloc(144 * 4);
  int* deg = (int*)alloc((size_t)N * 4);
  int* rowptr = (int*)alloc((size_t)(N + 1) * 4);
  int* cursor = (int*)alloc((size_t)N * 4);
  int* slist = (int*)alloc((size_t)ET * 4);
  (void)ws_size; (void)n_in; (void)out_size;

  k_prep<<<72, 64, 0, stream>>>(lin_w, att_src, att_dst, vbuf);
  k_fold<<<dim3(12, 73), 96, 0, stream>>>(lin_w, gat_bias, w_ih, b_ih, WW);
  k_av<<<(N + 255) / 256, 256, 0, stream>>>(x, vbuf, a_srcb, a_dstb, deg, N);
  k_count<<<(ET + 255) / 256, 256, 0, stream>>>(ei + E, deg, E, ET);
  k_scan<<<1, 1024, 0, stream>>>(deg, rowptr, cursor, N);
  k_scatter<<<(ET + 255) / 256, 256, 0, stream>>>(ei, ei + E, cursor, slist,
                                                  E, ET);
  k_aggx<<<(N + 3) / 4, 256, 0, stream>>>(x, a_srcb, a_dstb, slist, rowptr,
                                          Yb, N);
  k_gi2<<<dim3((N + 63) / 64, 12), 128, 0, stream>>>(Yb, WW, gib, N);
  k_rec<<<(N + 7) / 8, 256, 0, stream>>>((const unsigned short*)gib, w_hh,
                                         b_hh, p1w, p1b, p2w, p2b,
                                         (float*)d_out, N);
}

// Round 7
// 129.026 us; speedup vs baseline: 2.6505x; 1.1366x over previous
//
#include <hip/hip_runtime.h>
#include <math.h>

#define HEADS 3
#define C_OUT 384
#define GAT_IN 24
#define HID 32
#define TSTEPS 12
#define NEG_SLOPE 0.2f
#define CAPW 64        // per-wave cached edges in k_aggx

__device__ __forceinline__ float sigm(float x) {
  return 1.f / (1.f + __expf(-x));
}
__device__ __forceinline__ float tanh_fast(float x) {
  return 2.f / (1.f + __expf(-2.f * x)) - 1.f;
}
__device__ __forceinline__ unsigned short f2bf(float x) {
  unsigned int u = __float_as_uint(x);
  unsigned int r = u + 0x7fffu + ((u >> 16) & 1u);
  return (unsigned short)(r >> 16);
}
__device__ __forceinline__ unsigned int packbf(float lo, float hi) {
  return (unsigned int)f2bf(lo) | ((unsigned int)f2bf(hi) << 16);
}
__device__ __forceinline__ float bf2f(unsigned short u) {
  return __uint_as_float((unsigned int)u << 16);
}
__device__ __forceinline__ float lrelu(float x) {
  return x >= 0.f ? x : NEG_SLOPE * x;
}

// ---------------- K_const: fold WW/bb (blocks 0..875) + v_src/v_dst --------
// fold: WW[t][k=h*24+j][g] = sum_c lin_w[(h*384+t*32+c)*24+j]/3 * wih[g][c]
//       WW[t][72][g]       = sum_c gat_bias[t*32+c] * wih[g][c] + bih[g]
// prep: vbuf[h*24+j] = sum_c att_src[h][c]*lin_w[(h*384+c)*24+j]; dst at +72
__global__ __launch_bounds__(96) void k_const(const float* __restrict__ lin_w,
                                              const float* __restrict__ gat_bias,
                                              const float* __restrict__ wih,
                                              const float* __restrict__ bih,
                                              const float* __restrict__ att_src,
                                              const float* __restrict__ att_dst,
                                              float* __restrict__ WW,
                                              float* __restrict__ vbuf) {
  int b = blockIdx.x;
  if (b < 876) {  // fold
    int t = b / 73, k = b % 73;
    int g = threadIdx.x;  // 0..95
    __shared__ float s_w[32];
    if (g < 32) {
      if (k < 72) {
        int h = k / 24, j = k % 24;
        s_w[g] = lin_w[(size_t)(h * C_OUT + t * 32 + g) * GAT_IN + j] * (1.f / 3.f);
      } else {
        s_w[g] = gat_bias[t * 32 + g];
      }
    }
    __syncthreads();
    const float* wrow = wih + (size_t)g * 32;
    float acc = 0.f;
#pragma unroll
    for (int c = 0; c < 32; ++c) acc += s_w[c] * wrow[c];
    if (k == 72) acc += bih[g];
    WW[((size_t)t * 73 + k) * 96 + g] = acc;
  } else {  // prep (single wave)
    int bb = b - 876;  // 0..71
    int h = bb / 24, j = bb % 24;
    int lane = threadIdx.x;
    if (lane >= 64) return;
    float as = 0.f, ad = 0.f;
    for (int c = lane; c < C_OUT; c += 64) {
      float wv = lin_w[(size_t)(h * C_OUT + c) * GAT_IN + j];
      as += att_src[h * C_OUT + c] * wv;
      ad += att_dst[h * C_OUT + c] * wv;
    }
#pragma unroll
    for (int off = 32; off >= 1; off >>= 1) {
      as += __shfl_xor(as, off, 64);
      ad += __shfl_xor(ad, off, 64);
    }
    if (lane == 0) {
      vbuf[h * 24 + j] = as;
      vbuf[72 + h * 24 + j] = ad;
    }
  }
}

// ---------------- K2b: a_src/a_dst = xf @ v.T (+ zero deg) -----------------
__global__ __launch_bounds__(256) void k_av(const float* __restrict__ xf,
                                            const float* __restrict__ vbuf,
                                            float* __restrict__ a_src,
                                            float* __restrict__ a_dst,
                                            int* __restrict__ deg, int N) {
  __shared__ float s_v[144];
  int tid = threadIdx.x;
  if (tid < 144) s_v[tid] = vbuf[tid];
  __syncthreads();
  int n = blockIdx.x * 256 + tid;
  if (n >= N) return;
  deg[n] = 0;
  float xv[24];
  const float4* xr = (const float4*)(xf + (size_t)n * GAT_IN);
#pragma unroll
  for (int q = 0; q < 6; ++q) {
    float4 t = xr[q];
    xv[4 * q] = t.x; xv[4 * q + 1] = t.y; xv[4 * q + 2] = t.z; xv[4 * q + 3] = t.w;
  }
#pragma unroll
  for (int h = 0; h < 3; ++h) {
    float as = 0.f, ad = 0.f;
#pragma unroll
    for (int j = 0; j < 24; ++j) {
      as += xv[j] * s_v[h * 24 + j];
      ad += xv[j] * s_v[72 + h * 24 + j];
    }
    a_src[n * 3 + h] = as;
    a_dst[n * 3 + h] = ad;
  }
}

// ---------------- CSR build ------------------------------------------------
__global__ void k_count(const int* __restrict__ edst, int* __restrict__ deg,
                        int E, int ET) {
  int e = blockIdx.x * blockDim.x + threadIdx.x;
  if (e >= ET) return;
  int d = (e < E) ? edst[e] : (e - E);
  atomicAdd(&deg[d], 1);
}

__global__ __launch_bounds__(1024) void k_scan(const int* __restrict__ deg,
                                               int* __restrict__ rowptr,
                                               int* __restrict__ cursor,
                                               int n) {
  __shared__ int s_wt[16];
  int tid = threadIdx.x, lane = tid & 63, w = tid >> 6;
  int carry = 0;
  for (int base = 0; base < n; base += 4096) {
    int idx = base + tid * 4;
    int v0 = (idx + 0 < n) ? deg[idx + 0] : 0;
    int v1 = (idx + 1 < n) ? deg[idx + 1] : 0;
    int v2 = (idx + 2 < n) ? deg[idx + 2] : 0;
    int v3 = (idx + 3 < n) ? deg[idx + 3] : 0;
    int s1 = v0 + v1, s2 = s1 + v2, s3 = s2 + v3;
    int v = s3;
#pragma unroll
    for (int off = 1; off < 64; off <<= 1) {
      int t = __shfl_up(v, off, 64);
      if (lane >= off) v += t;
    }
    if (lane == 63) s_wt[w] = v;
    __syncthreads();
    if (w == 0) {
      int x = (lane < 16) ? s_wt[lane] : 0;
#pragma unroll
      for (int off = 1; off < 16; off <<= 1) {
        int t = __shfl_up(x, off, 64);
        if (lane >= off) x += t;
      }
      if (lane < 16) s_wt[lane] = x;
    }
    __syncthreads();
    int wexcl = (w == 0) ? 0 : s_wt[w - 1];
    int total = s_wt[15];
    int excl = carry + wexcl + v - s3;
    if (idx + 0 < n) { rowptr[idx + 0] = excl;      cursor[idx + 0] = excl; }
    if (idx + 1 < n) { rowptr[idx + 1] = excl + v0; cursor[idx + 1] = excl + v0; }
    if (idx + 2 < n) { rowptr[idx + 2] = excl + s1; cursor[idx + 2] = excl + s1; }
    if (idx + 3 < n) { rowptr[idx + 3] = excl + s2; cursor[idx + 3] = excl + s2; }
    carry += total;
    __syncthreads();
  }
  if (tid == 0) rowptr[n] = carry;
}

__global__ void k_scatter(const int* __restrict__ esrc,
                          const int* __restrict__ edst,
                          int* __restrict__ cursor, int* __restrict__ slist,
                          int E, int ET) {
  int e = blockIdx.x * blockDim.x + threadIdx.x;
  if (e >= ET) return;
  int d, s;
  if (e < E) { d = edst[e]; s = esrc[e]; }
  else { d = e - E; s = e - E; }
  int pos = atomicAdd(&cursor[d], 1);
  slist[pos] = s;
}

// ---------------- K6: softmax + xf-space aggregation (L2-resident) ---------
__global__ __launch_bounds__(256) void k_aggx(
    const float* __restrict__ xf, const float* __restrict__ a_src,
    const float* __restrict__ a_dst, const int* __restrict__ slist,
    const int* __restrict__ rowptr, float* __restrict__ Y, int N) {
  __shared__ int s_src[4][CAPW];
  __shared__ float s_w[4][CAPW][3];
  int tid = threadIdx.x, lane = tid & 63, wv = tid >> 6;
  int n = blockIdx.x * 4 + wv;
  if (n >= N) return;  // per-wave exit; no barriers used
  int start = rowptr[n], deg = rowptr[n + 1] - start;
  float ad0 = a_dst[n * 3 + 0], ad1 = a_dst[n * 3 + 1], ad2 = a_dst[n * 3 + 2];

  // pass A: exp(alpha) + wave-sum (logits bounded => no max-shift needed)
  float t0 = 0.f, t1 = 0.f, t2 = 0.f;
  for (int i = lane; i < deg; i += 64) {
    int s = slist[start + i];
    float e0 = __expf(lrelu(a_src[s * 3 + 0] + ad0));
    float e1 = __expf(lrelu(a_src[s * 3 + 1] + ad1));
    float e2 = __expf(lrelu(a_src[s * 3 + 2] + ad2));
    if (i < CAPW) {
      s_src[wv][i] = s;
      s_w[wv][i][0] = e0; s_w[wv][i][1] = e1; s_w[wv][i][2] = e2;
    }
    t0 += e0; t1 += e1; t2 += e2;
  }
#pragma unroll
  for (int off = 32; off >= 1; off >>= 1) {
    t0 += __shfl_xor(t0, off, 64);
    t1 += __shfl_xor(t1, off, 64);
    t2 += __shfl_xor(t2, off, 64);
  }
  float inv0 = 1.f / t0, inv1 = 1.f / t1, inv2 = 1.f / t2;

  // pass B: 2 edge-slots x 24 active channel-lanes; xf gather is L2-resident
  int eg = lane >> 5;   // edge slot 0/1
  int c = lane & 31;    // channel (active c<24)
  float acc0 = 0.f, acc1 = 0.f, acc2 = 0.f;
  if (deg <= CAPW) {
#pragma unroll 2
    for (int i = eg; i < deg; i += 2) {
      int s = s_src[wv][i];
      float w0 = s_w[wv][i][0] * inv0;
      float w1 = s_w[wv][i][1] * inv1;
      float w2 = s_w[wv][i][2] * inv2;
      float xv = (c < 24) ? xf[(size_t)s * 24 + c] : 0.f;
      acc0 += w0 * xv; acc1 += w1 * xv; acc2 += w2 * xv;
    }
  } else {
    for (int i = eg; i < deg; i += 2) {
      int s = slist[start + i];
      float w0 = __expf(lrelu(a_src[s * 3 + 0] + ad0)) * inv0;
      float w1 = __expf(lrelu(a_src[s * 3 + 1] + ad1)) * inv1;
      float w2 = __expf(lrelu(a_src[s * 3 + 2] + ad2)) * inv2;
      float xv = (c < 24) ? xf[(size_t)s * 24 + c] : 0.f;
      acc0 += w0 * xv; acc1 += w1 * xv; acc2 += w2 * xv;
    }
  }
  acc0 += __shfl_xor(acc0, 32, 64);
  acc1 += __shfl_xor(acc1, 32, 64);
  acc2 += __shfl_xor(acc2, 32, 64);
  if (lane < 24) {
    float* yr = Y + (size_t)n * 72;
    yr[lane] = acc0;
    yr[24 + lane] = acc1;
    yr[48 + lane] = acc2;
  }
}

// ---------------- K_gi2: gi(bf16) = Y @ WW[t] + bb[t], K-chunked -----------
// 64 rows x 96 cols per 128-thread block; K=72 staged in 3 chunks of 24
// => LDS 16.5 KB (was 48 KB) => ~9 blocks/CU residency.
__global__ __launch_bounds__(128) void k_gi2(const float* __restrict__ Y,
                                             const float* __restrict__ WW,
                                             unsigned int* __restrict__ gi,
                                             int N) {
  __shared__ float At[24][68];
  __shared__ float Bt[24][100];
  __shared__ float s_bias[96];
  int tid = threadIdx.x;
  int row0 = blockIdx.x * 64;
  int t = blockIdx.y;
  const float* WWt = WW + (size_t)t * 73 * 96;
  if (tid < 96) s_bias[tid] = WWt[72 * 96 + tid];
  int r0 = (tid & 7) * 8, c0 = (tid >> 3) * 6;
  float acc[8][6];
#pragma unroll
  for (int i = 0; i < 8; ++i)
#pragma unroll
    for (int j = 0; j < 6; ++j) acc[i][j] = 0.f;

  int r = tid >> 1, half = tid & 1;
  int rc = min(row0 + r, N - 1);
#pragma unroll
  for (int ch = 0; ch < 3; ++ch) {
    // stage A chunk: 64 rows x 24 k
    {
      const float4* yr =
          (const float4*)(Y + (size_t)rc * 72 + ch * 24 + half * 12);
#pragma unroll
      for (int q = 0; q < 3; ++q) {
        float4 a = yr[q];
        int kk = half * 12 + q * 4;
        At[kk + 0][r] = a.x; At[kk + 1][r] = a.y;
        At[kk + 2][r] = a.z; At[kk + 3][r] = a.w;
      }
    }
    // stage B chunk: 24 k x 96 g
#pragma unroll
    for (int fid = tid; fid < 576; fid += 128) {
      int k = fid / 24, gq = (fid % 24) * 4;
      float4 b = *(const float4*)(WWt + (size_t)(ch * 24 + k) * 96 + gq);
      Bt[k][gq + 0] = b.x; Bt[k][gq + 1] = b.y;
      Bt[k][gq + 2] = b.z; Bt[k][gq + 3] = b.w;
    }
    __syncthreads();
#pragma unroll 4
    for (int k = 0; k < 24; ++k) {
      float4 a0 = *(const float4*)&At[k][r0];
      float4 a1 = *(const float4*)&At[k][r0 + 4];
      float2 b0 = *(const float2*)&Bt[k][c0];
      float2 b1 = *(const float2*)&Bt[k][c0 + 2];
      float2 b2 = *(const float2*)&Bt[k][c0 + 4];
      float b[6] = {b0.x, b0.y, b1.x, b1.y, b2.x, b2.y};
      float av[8] = {a0.x, a0.y, a0.z, a0.w, a1.x, a1.y, a1.z, a1.w};
#pragma unroll
      for (int i = 0; i < 8; ++i)
#pragma unroll
        for (int j = 0; j < 6; ++j) acc[i][j] += av[i] * b[j];
    }
    __syncthreads();
  }
#pragma unroll
  for (int i = 0; i < 8; ++i) {
    int n = row0 + r0 + i;
    if (n < N) {
      unsigned int* crow = gi + (size_t)n * 576 + (t * 96 + c0) / 2;
#pragma unroll
      for (int jj = 0; jj < 3; ++jj) {
        float lo = acc[i][2 * jj] + s_bias[c0 + 2 * jj];
        float hi = acc[i][2 * jj + 1] + s_bias[c0 + 2 * jj + 1];
        crow[jj] = packbf(lo, hi);
      }
    }
  }
}

// ---------------- K7b: GRU recurrence + projections ------------------------
__global__ __launch_bounds__(256) void k_rec(
    const unsigned short* __restrict__ gi, const float* __restrict__ whh,
    const float* __restrict__ bhh, const float* __restrict__ p1w,
    const float* __restrict__ p1b, const float* __restrict__ p2w,
    const float* __restrict__ p2b, float* __restrict__ out, int N) {
  __shared__ float h_hist[8][13][36];
  __shared__ float s_o[8][12];
  int tid = threadIdx.x;
  int nd = tid >> 5;
  int k = tid & 31;
  int node = blockIdx.x * 8 + nd;
  if (node >= N) return;  // no barriers below -> safe

  float wr[32], wz[32], wn[32];
  {
    const float4* pr = (const float4*)(whh + (size_t)k * HID);
    const float4* pz = (const float4*)(whh + (size_t)(HID + k) * HID);
    const float4* pn = (const float4*)(whh + (size_t)(2 * HID + k) * HID);
#pragma unroll
    for (int j = 0; j < 8; ++j) {
      float4 a = pr[j], b = pz[j], c = pn[j];
      wr[4 * j] = a.x; wr[4 * j + 1] = a.y; wr[4 * j + 2] = a.z; wr[4 * j + 3] = a.w;
      wz[4 * j] = b.x; wz[4 * j + 1] = b.y; wz[4 * j + 2] = b.z; wz[4 * j + 3] = b.w;
      wn[4 * j] = c.x; wn[4 * j + 1] = c.y; wn[4 * j + 2] = c.z; wn[4 * j + 3] = c.w;
    }
  }
  float bhr = bhh[k], bhz = bhh[HID + k], bhn = bhh[2 * HID + k];
  h_hist[nd][0][k] = 0.f;
  float h = 0.f;
  const unsigned short* girow = gi + (size_t)node * TSTEPS * 96;
  for (int t = 0; t < TSTEPS; ++t) {
    float gr = bf2f(girow[t * 96 + k]);
    float gz = bf2f(girow[t * 96 + 32 + k]);
    float gn = bf2f(girow[t * 96 + 64 + k]);
    float ar = 0.f, az = 0.f, an = 0.f;
    const float* hh = &h_hist[nd][t][0];
#pragma unroll
    for (int q = 0; q < 8; ++q) {
      float4 hp = *(const float4*)(hh + q * 4);
      ar += wr[4 * q] * hp.x + wr[4 * q + 1] * hp.y + wr[4 * q + 2] * hp.z +
            wr[4 * q + 3] * hp.w;
      az += wz[4 * q] * hp.x + wz[4 * q + 1] * hp.y + wz[4 * q + 2] * hp.z +
            wz[4 * q + 3] * hp.w;
      an += wn[4 * q] * hp.x + wn[4 * q + 1] * hp.y + wn[4 * q + 2] * hp.z +
            wn[4 * q + 3] * hp.w;
    }
    float r = sigm(gr + ar + bhr);
    float z = sigm(gz + az + bhz);
    float nn = tanh_fast(gn + r * (an + bhn));
    float hnew = (1.f - z) * nn + z * h;
    h = hnew;
    h_hist[nd][t + 1][k] = hnew;
  }
  if (k < TSTEPS) {
    float o = p1b[0];
#pragma unroll
    for (int kk = 0; kk < HID; ++kk) o += h_hist[nd][k + 1][kk] * p1w[kk];
    s_o[nd][k] = o;
  }
  if (k < TSTEPS) {
    float acc = p2b[k];
#pragma unroll
    for (int s2 = 0; s2 < TSTEPS; ++s2)
      acc += p2w[k * TSTEPS + s2] * s_o[nd][s2];
    out[(size_t)node * TSTEPS + k] = acc;
  }
}

// ---------------------------------------------------------------------------
extern "C" void kernel_launch(void* const* d_in, const int* in_sizes, int n_in,
                              void* d_out, int out_size, void* d_ws,
                              size_t ws_size, hipStream_t stream) {
  const float* x = (const float*)d_in[0];
  const int* ei = (const int*)d_in[1];
  const float* lin_w = (const float*)d_in[2];
  const float* att_src = (const float*)d_in[3];
  const float* att_dst = (const float*)d_in[4];
  const float* gat_bias = (const float*)d_in[5];
  const float* w_ih = (const float*)d_in[6];
  const float* w_hh = (const float*)d_in[7];
  const float* b_ih = (const float*)d_in[8];
  const float* b_hh = (const float*)d_in[9];
  const float* p1w = (const float*)d_in[10];
  const float* p1b = (const float*)d_in[11];
  const float* p2w = (const float*)d_in[12];
  const float* p2b = (const float*)d_in[13];

  int N = in_sizes[0] / GAT_IN;  // 10000
  int E = in_sizes[1] / 2;       // 160000
  int ET = E + N;

  size_t off = 0;
  char* base = (char*)d_ws;
  auto alloc = [&](size_t bytes) {
    void* p = base + off;
    off += (bytes + 255) & ~(size_t)255;
    return p;
  };
  unsigned int* gib = (unsigned int*)alloc((size_t)N * 576 * 4);  // bf16 gi
  float* Yb = (float*)alloc((size_t)N * 72 * 4);
  float* WW = (float*)alloc((size_t)12 * 73 * 96 * 4);
  float* a_srcb = (float*)alloc((size_t)N * 3 * 4);
  float* a_dstb = (float*)alloc((size_t)N * 3 * 4);
  float* vbuf = (float*)alloc(144 * 4);
  int* deg = (int*)alloc((size_t)N * 4);
  int* rowptr = (int*)alloc((size_t)(N + 1) * 4);
  int* cursor = (int*)alloc((size_t)N * 4);
  int* slist = (int*)alloc((size_t)ET * 4);
  (void)ws_size; (void)n_in; (void)out_size;

  k_const<<<948, 96, 0, stream>>>(lin_w, gat_bias, w_ih, b_ih, att_src,
                                  att_dst, WW, vbuf);
  k_av<<<(N + 255) / 256, 256, 0, stream>>>(x, vbuf, a_srcb, a_dstb, deg, N);
  k_count<<<(ET + 255) / 256, 256, 0, stream>>>(ei + E, deg, E, ET);
  k_scan<<<1, 1024, 0, stream>>>(deg, rowptr, cursor, N);
  k_scatter<<<(ET + 255) / 256, 256, 0, stream>>>(ei, ei + E, cursor, slist,
                                                  E, ET);
  k_aggx<<<(N + 3) / 4, 256, 0, stream>>>(x, a_srcb, a_dstb, slist, rowptr,
                                          Yb, N);
  k_gi2<<<dim3((N + 63) / 64, 12), 128, 0, stream>>>(Yb, WW, gib, N);
  k_rec<<<(N + 7) / 8, 256, 0, stream>>>((const unsigned short*)gib, w_hh,
                                         b_hh, p1w, p1b, p2w, p2b,
                                         (float*)d_out, N);
}